// Round 3
// baseline (5367.932 us; speedup 1.0000x reference)
//
#include <hip/hip_runtime.h>
#include <math.h>

#define N_NODES 100000
#define N_EDGES 600000

// ---------------------------------------------------------------------------
// Generic tiled GEMM: C[M,Nc] = act(A[M,K] @ W[K,Nc] + b[Nc])
// act==1: bias+relu; act==0: plain matmul (b may be null).
// Requirements: K % 32 == 0, Nc % 64 == 0. Row guard on M.
// 256 threads, BM=64, BN=64, BK=32, per-thread 4x4 micro-tile.
// Broadcast-friendly mapping: a-reads unique per row_t (16-lane broadcast),
// b-reads unique per col_t (4-way broadcast) -> LDS unique-traffic ~10B/cyc/CU,
// far under bank ceiling => FMA-issue-bound.
// ---------------------------------------------------------------------------
__global__ __launch_bounds__(256) void gemm_bias_relu(
    const float* __restrict__ A, const float* __restrict__ W,
    const float* __restrict__ b, float* __restrict__ C,
    int M, int K, int Nc, int act)
{
    __shared__ float As[64][36];   // stride 36: 144B rows, 16B aligned
    __shared__ float Ws[32][68];   // stride 68: 272B rows, 16B aligned

    const int tid   = threadIdx.x;
    const int row_t = tid >> 4;    // 0..15 -> rows row_t*4..+3
    const int col_t = tid & 15;    // 0..15 -> cols col_t*4..+3
    const int rowBase = blockIdx.x * 64;
    const int colBase = blockIdx.y * 64;

    float acc[4][4] = {};

    for (int kb = 0; kb < K; kb += 32) {
        // stage A tile [64][32]
        #pragma unroll
        for (int i = 0; i < 2; ++i) {
            int f = tid + i * 256;            // 0..511
            int r = f >> 3, c4 = (f & 7) << 2;
            int row = rowBase + r;
            float4 v = make_float4(0.f, 0.f, 0.f, 0.f);
            if (row < M) v = *(const float4*)(A + (size_t)row * K + kb + c4);
            *(float4*)&As[r][c4] = v;
        }
        // stage W tile [32][64]
        #pragma unroll
        for (int i = 0; i < 2; ++i) {
            int f = tid + i * 256;
            int r = f >> 4, c4 = (f & 15) << 2;
            *(float4*)&Ws[r][c4] = *(const float4*)(W + (size_t)(kb + r) * Nc + colBase + c4);
        }
        __syncthreads();
        #pragma unroll
        for (int k4 = 0; k4 < 8; ++k4) {
            float4 a[4], bb[4];
            #pragma unroll
            for (int i = 0; i < 4; ++i)
                a[i] = *(const float4*)&As[row_t * 4 + i][k4 * 4];
            #pragma unroll
            for (int kk = 0; kk < 4; ++kk)
                bb[kk] = *(const float4*)&Ws[k4 * 4 + kk][col_t * 4];
            const float* ap = reinterpret_cast<const float*>(a);
            const float* bp = reinterpret_cast<const float*>(bb);
            #pragma unroll
            for (int kk = 0; kk < 4; ++kk)
                #pragma unroll
                for (int i = 0; i < 4; ++i)
                    #pragma unroll
                    for (int j = 0; j < 4; ++j)
                        acc[i][j] = fmaf(ap[i * 4 + kk], bp[kk * 4 + j], acc[i][j]);
        }
        __syncthreads();
    }

    float4 bias = make_float4(0.f, 0.f, 0.f, 0.f);
    if (act) bias = *(const float4*)(b + colBase + col_t * 4);
    #pragma unroll
    for (int i = 0; i < 4; ++i) {
        int row = rowBase + row_t * 4 + i;
        if (row < M) {
            float4 o;
            o.x = acc[i][0] + bias.x;
            o.y = acc[i][1] + bias.y;
            o.z = acc[i][2] + bias.z;
            o.w = acc[i][3] + bias.w;
            if (act) {
                o.x = fmaxf(o.x, 0.f); o.y = fmaxf(o.y, 0.f);
                o.z = fmaxf(o.z, 0.f); o.w = fmaxf(o.w, 0.f);
            }
            *(float4*)(C + (size_t)row * Nc + colBase + col_t * 4) = o;
        }
    }
}

// ---------------------------------------------------------------------------
// Repack W_e11 [256,128] into Wcat [128,256]:
//   Wcat[k][j]      = W_e11[k][j]        (j < 128,  "W_top" for src rows)
//   Wcat[k][128+j'] = W_e11[128+k][j']   (j >= 128, "W_bot" for dst rows)
// so that uv = x @ Wcat gives u = uv[:, :128], v = uv[:, 128:], and
// [x_src; x_dst] @ W_e11 == u[src] + v[dst]  (exact fp32 refactor).
// ---------------------------------------------------------------------------
__global__ __launch_bounds__(256) void repack_We11(
    const float* __restrict__ We11, float* __restrict__ Wcat)
{
    int idx = blockIdx.x * 256 + threadIdx.x;   // 0..32767
    int k = idx >> 8;        // 0..127
    int j = idx & 255;       // 0..255
    float v = (j < 128) ? We11[k * 128 + j] : We11[(128 + k) * 128 + (j - 128)];
    Wcat[idx] = v;
}

// ---------------------------------------------------------------------------
// Fused edge pipeline, 32 edges per block. Layer 1 is pre-factored per node:
//   h1[e] = relu(uv[src[e]][0:128] + uv[dst[e]][128:256] + b_e11)  (gather+add)
//   h2    = relu(h1 @ W_e12 + b_e12)                               (K=128 GEMM)
//   if store_z: z[e] = h2; preds[e] = sigmoid(h2 . W_dec + b_dec)  (fused dec)
//   else:       atomicAdd h2 into x2h[src][0:128], x2h[dst][128:256]
// ---------------------------------------------------------------------------
__global__ __launch_bounds__(256) void edge_fused(
    const float* __restrict__ uv,          // [N,256] = [x@W_top | x@W_bot]
    const int* __restrict__ src, const int* __restrict__ dst,
    const float* __restrict__ be1,         // [128]
    const float* __restrict__ We2, const float* __restrict__ be2,   // [128,128],[128]
    const float* __restrict__ Wd, const float* __restrict__ bd,     // [128,1],[1]
    float* __restrict__ x2h,               // [N,256] atomic accumulator
    float* __restrict__ z,                 // [E,128]
    float* __restrict__ preds,             // [E]
    int store_z)
{
    __shared__ float H1[32][132];  // layer-1 output, stride 132 (528B rows)
    __shared__ float Ws[32][132];  // weight K-chunk
    __shared__ float red[32][33];  // decoder partial-dot reduction
    __shared__ int   sidx[32], didx[32];

    const int tid   = threadIdx.x;
    const int ebase = blockIdx.x * 32;

    if (tid < 32)       sidx[tid]      = src[ebase + tid];
    else if (tid < 64)  didx[tid - 32] = dst[ebase + tid - 32];
    __syncthreads();

    // ---- layer 1: gather u[src] + v[dst] + bias, relu -> H1 ----
    const int wave = tid >> 6, lane = tid & 63;
    const float2 bias1 = *(const float2*)(be1 + lane * 2);
    #pragma unroll
    for (int i = 0; i < 8; ++i) {
        int e = wave * 8 + i;
        int s = sidx[e], d = didx[e];
        float2 a = *(const float2*)(uv + (size_t)s * 256 + lane * 2);
        float2 b = *(const float2*)(uv + (size_t)d * 256 + 128 + lane * 2);
        float2 h;
        h.x = fmaxf(a.x + b.x + bias1.x, 0.f);
        h.y = fmaxf(a.y + b.y + bias1.y, 0.f);
        *(float2*)&H1[e][lane * 2] = h;
    }

    const int col_t = tid & 31;   // cols col_t*4..+3  (128 cols)
    const int row_t = tid >> 5;   // rows row_t*4..+3  (32 rows)

    // ---- layer 2: h2 = relu(H1 @ We2 + be2), K=128 ----
    float acc2[4][4] = {};
    for (int kb = 0; kb < 128; kb += 32) {
        __syncthreads();    // H1 visibility (first) / Ws reuse (subsequent)
        #pragma unroll
        for (int i = 0; i < 4; ++i) {
            int f = tid + i * 256;
            int r = f >> 5, c4 = (f & 31) << 2;
            *(float4*)&Ws[r][c4] = *(const float4*)(We2 + (size_t)(kb + r) * 128 + c4);
        }
        __syncthreads();
        #pragma unroll
        for (int k4 = 0; k4 < 8; ++k4) {
            float4 a[4], bb[4];
            #pragma unroll
            for (int i = 0; i < 4; ++i)
                a[i] = *(const float4*)&H1[row_t * 4 + i][kb + k4 * 4];
            #pragma unroll
            for (int kk = 0; kk < 4; ++kk)
                bb[kk] = *(const float4*)&Ws[k4 * 4 + kk][col_t * 4];
            const float* ap = reinterpret_cast<const float*>(a);
            const float* bp = reinterpret_cast<const float*>(bb);
            #pragma unroll
            for (int kk = 0; kk < 4; ++kk)
                #pragma unroll
                for (int i = 0; i < 4; ++i)
                    #pragma unroll
                    for (int j = 0; j < 4; ++j)
                        acc2[i][j] = fmaf(ap[i * 4 + kk], bp[kk * 4 + j], acc2[i][j]);
        }
    }

    const float4 be2v = *(const float4*)(be2 + col_t * 4);
    if (store_z) {
        // last iteration: write z and fused decoder (no scatter; the reference
        // discards the final concat)
        const float4 wd = *(const float4*)(Wd + col_t * 4);
        #pragma unroll
        for (int i = 0; i < 4; ++i) {
            int e = ebase + row_t * 4 + i;
            float4 o;
            o.x = fmaxf(acc2[i][0] + be2v.x, 0.f);
            o.y = fmaxf(acc2[i][1] + be2v.y, 0.f);
            o.z = fmaxf(acc2[i][2] + be2v.z, 0.f);
            o.w = fmaxf(acc2[i][3] + be2v.w, 0.f);
            *(float4*)(z + (size_t)e * 128 + col_t * 4) = o;
            red[row_t * 4 + i][col_t] =
                o.x * wd.x + o.y * wd.y + o.z * wd.z + o.w * wd.w;
        }
        __syncthreads();
        if (tid < 32) {
            float s = 0.f;
            #pragma unroll
            for (int c = 0; c < 32; ++c) s += red[tid][c];
            preds[ebase + tid] = 1.f / (1.f + expf(-(s + bd[0])));
        }
    } else {
        #pragma unroll
        for (int i = 0; i < 4; ++i) {
            int r = row_t * 4 + i;
            float4 o;
            o.x = fmaxf(acc2[i][0] + be2v.x, 0.f);
            o.y = fmaxf(acc2[i][1] + be2v.y, 0.f);
            o.z = fmaxf(acc2[i][2] + be2v.z, 0.f);
            o.w = fmaxf(acc2[i][3] + be2v.w, 0.f);
            int s = sidx[r], d = didx[r];
            float* ps = x2h + (size_t)s * 256 + col_t * 4;
            atomicAdd(ps + 0, o.x); atomicAdd(ps + 1, o.y);
            atomicAdd(ps + 2, o.z); atomicAdd(ps + 3, o.w);
            float* pd = x2h + (size_t)d * 256 + 128 + col_t * 4;
            atomicAdd(pd + 0, o.x); atomicAdd(pd + 1, o.y);
            atomicAdd(pd + 2, o.z); atomicAdd(pd + 3, o.w);
        }
    }
}

// ---------------------------------------------------------------------------
extern "C" void kernel_launch(void* const* d_in, const int* in_sizes, int n_in,
                              void* d_out, int out_size, void* d_ws, size_t ws_size,
                              hipStream_t stream)
{
    const float* inputs = (const float*)d_in[0];
    const float* W_n11  = (const float*)d_in[1];
    const float* b_n11  = (const float*)d_in[2];
    const float* W_n21  = (const float*)d_in[3];
    const float* b_n21  = (const float*)d_in[4];
    const float* W_n22  = (const float*)d_in[5];
    const float* b_n22  = (const float*)d_in[6];
    const float* W_e11  = (const float*)d_in[7];
    const float* b_e11  = (const float*)d_in[8];
    const float* W_e12  = (const float*)d_in[9];
    const float* b_e12  = (const float*)d_in[10];
    const float* W_dec  = (const float*)d_in[11];
    const float* b_dec  = (const float*)d_in[12];
    const int*   src    = (const int*)d_in[13];
    const int*   dst    = (const int*)d_in[14];

    // workspace: x2h [N,256] | uv [N,256] | Wcat [128,256]   (~205 MB)
    float* x2h  = (float*)d_ws;
    float* uv   = x2h + (size_t)N_NODES * 256;
    float* Wcat = uv  + (size_t)N_NODES * 256;

    float* preds = (float*)d_out;
    float* z     = preds + N_EDGES;     // [E,128] region of d_out

    // tmp/xh live in the z region of d_out: both are dead before the final
    // edge_fused overwrites z (same-stream ordering; edge_fused reads only uv).
    float* tmp = z;                         // [N,128]
    float* xh  = z + (size_t)N_NODES * 128; // [N,128]

    const int rowTiles = (N_NODES + 63) / 64;   // 1563

    // per-launch weight repack for the factored edge layer 1
    repack_We11<<<128, 256, 0, stream>>>(W_e11, Wcat);

    // node encoder: [N,64] -> [N,256]
    gemm_bias_relu<<<dim3(rowTiles, 4), 256, 0, stream>>>(
        inputs, W_n11, b_n11, x2h, N_NODES, 64, 256, 1);

    for (int it = 0; it < 3; ++it) {
        const int last = (it == 2);
        // node MLP: [N,256] -> [N,128] -> [N,128]
        gemm_bias_relu<<<dim3(rowTiles, 2), 256, 0, stream>>>(
            x2h, W_n21, b_n21, tmp, N_NODES, 256, 128, 1);
        gemm_bias_relu<<<dim3(rowTiles, 2), 256, 0, stream>>>(
            tmp, W_n22, b_n22, xh, N_NODES, 128, 128, 1);
        // factored edge layer 1, node side: uv = xh @ Wcat (no bias/act)
        gemm_bias_relu<<<dim3(rowTiles, 4), 256, 0, stream>>>(
            xh, Wcat, nullptr, uv, N_NODES, 128, 256, 0);
        // zero the scatter accumulator (skipped on last iter: no scatter)
        if (!last)
            hipMemsetAsync(x2h, 0, (size_t)N_NODES * 256 * sizeof(float), stream);
        // fused gather-add-relu -> edge L2 GEMM -> (scatter | z-store + decoder)
        edge_fused<<<N_EDGES / 32, 256, 0, stream>>>(
            uv, src, dst, b_e11, W_e12, b_e12, W_dec, b_dec, x2h, z, preds, last);
    }
}

// Round 4
// 2411.600 us; speedup vs baseline: 2.2259x; 2.2259x over previous
//
#include <hip/hip_runtime.h>
#include <math.h>

#define N_NODES 100000
#define N_EDGES 600000
#define SCAN_CHUNK 1024

// ---------------------------------------------------------------------------
// Generic tiled GEMM: C[M,Nc] = act(A[M,K] @ W[K,Nc] + b[Nc])
// act==1: bias+relu; act==0: plain matmul (b may be null).
// K % 32 == 0, Nc % 64 == 0. Row guard on M. 256 thr, BM=64,BN=64,BK=32, 4x4.
// ---------------------------------------------------------------------------
__global__ __launch_bounds__(256) void gemm_bias_relu(
    const float* __restrict__ A, const float* __restrict__ W,
    const float* __restrict__ b, float* __restrict__ C,
    int M, int K, int Nc, int act)
{
    __shared__ float As[64][36];
    __shared__ float Ws[32][68];

    const int tid   = threadIdx.x;
    const int row_t = tid >> 4;
    const int col_t = tid & 15;
    const int rowBase = blockIdx.x * 64;
    const int colBase = blockIdx.y * 64;

    float acc[4][4] = {};

    for (int kb = 0; kb < K; kb += 32) {
        #pragma unroll
        for (int i = 0; i < 2; ++i) {
            int f = tid + i * 256;
            int r = f >> 3, c4 = (f & 7) << 2;
            int row = rowBase + r;
            float4 v = make_float4(0.f, 0.f, 0.f, 0.f);
            if (row < M) v = *(const float4*)(A + (size_t)row * K + kb + c4);
            *(float4*)&As[r][c4] = v;
        }
        #pragma unroll
        for (int i = 0; i < 2; ++i) {
            int f = tid + i * 256;
            int r = f >> 4, c4 = (f & 15) << 2;
            *(float4*)&Ws[r][c4] = *(const float4*)(W + (size_t)(kb + r) * Nc + colBase + c4);
        }
        __syncthreads();
        #pragma unroll
        for (int k4 = 0; k4 < 8; ++k4) {
            float4 a[4], bb[4];
            #pragma unroll
            for (int i = 0; i < 4; ++i)
                a[i] = *(const float4*)&As[row_t * 4 + i][k4 * 4];
            #pragma unroll
            for (int kk = 0; kk < 4; ++kk)
                bb[kk] = *(const float4*)&Ws[k4 * 4 + kk][col_t * 4];
            const float* ap = reinterpret_cast<const float*>(a);
            const float* bp = reinterpret_cast<const float*>(bb);
            #pragma unroll
            for (int kk = 0; kk < 4; ++kk)
                #pragma unroll
                for (int i = 0; i < 4; ++i)
                    #pragma unroll
                    for (int j = 0; j < 4; ++j)
                        acc[i][j] = fmaf(ap[i * 4 + kk], bp[kk * 4 + j], acc[i][j]);
        }
        __syncthreads();
    }

    float4 bias = make_float4(0.f, 0.f, 0.f, 0.f);
    if (act) bias = *(const float4*)(b + colBase + col_t * 4);
    #pragma unroll
    for (int i = 0; i < 4; ++i) {
        int row = rowBase + row_t * 4 + i;
        if (row < M) {
            float4 o;
            o.x = acc[i][0] + bias.x;
            o.y = acc[i][1] + bias.y;
            o.z = acc[i][2] + bias.z;
            o.w = acc[i][3] + bias.w;
            if (act) {
                o.x = fmaxf(o.x, 0.f); o.y = fmaxf(o.y, 0.f);
                o.z = fmaxf(o.z, 0.f); o.w = fmaxf(o.w, 0.f);
            }
            *(float4*)(C + (size_t)row * Nc + colBase + col_t * 4) = o;
        }
    }
}

// ---------------------------------------------------------------------------
// Repack W_e11 [256,128] -> Wcat [128,256]:  uv = x @ Wcat gives
// [x_src;x_dst] @ W_e11 == uv[src][:128] + uv[dst][128:]  (exact fp32 refactor)
// ---------------------------------------------------------------------------
__global__ __launch_bounds__(256) void repack_We11(
    const float* __restrict__ We11, float* __restrict__ Wcat)
{
    int idx = blockIdx.x * 256 + threadIdx.x;
    int k = idx >> 8;
    int j = idx & 255;
    float v = (j < 128) ? We11[k * 128 + j] : We11[(128 + k) * 128 + (j - 128)];
    Wcat[idx] = v;
}

// ---------------------------------------------------------------------------
// CSR build: histogram -> in-place exclusive scan (3 phases) -> fill perm
// ---------------------------------------------------------------------------
__global__ __launch_bounds__(256) void edge_hist(
    const int* __restrict__ src, const int* __restrict__ dst,
    int* __restrict__ cs, int* __restrict__ cd)
{
    int e = blockIdx.x * 256 + threadIdx.x;
    if (e < N_EDGES) {
        atomicAdd(&cs[src[e]], 1);
        atomicAdd(&cd[dst[e]], 1);
    }
}

// in-place exclusive scan, phase 1: per-block (1024 elems) local scan + total
__global__ __launch_bounds__(256) void scan_phase1(
    int* __restrict__ a, int* __restrict__ bsum, int n)
{
    __shared__ int s[256];
    const int t = threadIdx.x;
    const int base = blockIdx.x * SCAN_CHUNK;
    int v[4], sum = 0;
    #pragma unroll
    for (int i = 0; i < 4; ++i) {
        int idx = base + t * 4 + i;
        v[i] = (idx < n) ? a[idx] : 0;
        sum += v[i];
    }
    s[t] = sum;
    __syncthreads();
    for (int off = 1; off < 256; off <<= 1) {
        int x = (t >= off) ? s[t - off] : 0;
        __syncthreads();
        s[t] += x;
        __syncthreads();
    }
    if (t == 255) bsum[blockIdx.x] = s[255];
    int run = s[t] - sum;   // exclusive prefix for this thread's 4 elems
    #pragma unroll
    for (int i = 0; i < 4; ++i) {
        int idx = base + t * 4 + i;
        if (idx < n) a[idx] = run;
        run += v[i];
    }
}

// phase 2: serial exclusive scan of block sums (nb ~ 98, trivial)
__global__ void scan_phase2(int* __restrict__ bsum, int nb)
{
    if (threadIdx.x == 0 && blockIdx.x == 0) {
        int run = 0;
        for (int b = 0; b < nb; ++b) { int x = bsum[b]; bsum[b] = run; run += x; }
    }
}

// phase 3: add block offset; also init cursor copy
__global__ __launch_bounds__(256) void scan_phase3(
    int* __restrict__ a, const int* __restrict__ bsum,
    int* __restrict__ cur, int n)
{
    int idx = blockIdx.x * 256 + threadIdx.x;
    if (idx < n) {
        int v = a[idx] + bsum[idx / SCAN_CHUNK];
        a[idx] = v;
        cur[idx] = v;
    }
}

__global__ __launch_bounds__(256) void edge_fill(
    const int* __restrict__ src, const int* __restrict__ dst,
    int* __restrict__ curs, int* __restrict__ curd,
    int* __restrict__ perms, int* __restrict__ permd)
{
    int e = blockIdx.x * 256 + threadIdx.x;
    if (e < N_EDGES) {
        int p1 = atomicAdd(&curs[src[e]], 1); perms[p1] = e;
        int p2 = atomicAdd(&curd[dst[e]], 1); permd[p2] = e;
    }
}

// ---------------------------------------------------------------------------
// Fused edge pipeline, 32 edges/block. Layer 1 pre-factored per node:
//   h1[e] = relu(uv[src][0:128] + uv[dst][128:256] + b_e11)
//   h2    = relu(h1 @ W_e12 + b_e12)
//   always: xe[e] = h2 (plain store; xe region == final z)
//   if last: preds[e] = sigmoid(h2 . W_dec + b_dec)
// ---------------------------------------------------------------------------
__global__ __launch_bounds__(256) void edge_fused(
    const float* __restrict__ uv,
    const int* __restrict__ src, const int* __restrict__ dst,
    const float* __restrict__ be1,
    const float* __restrict__ We2, const float* __restrict__ be2,
    const float* __restrict__ Wd, const float* __restrict__ bd,
    float* __restrict__ xe,                // [E,128]
    float* __restrict__ preds,             // [E]
    int last)
{
    __shared__ float H1[32][132];
    __shared__ float Ws[32][132];
    __shared__ float red[32][33];
    __shared__ int   sidx[32], didx[32];

    const int tid   = threadIdx.x;
    const int ebase = blockIdx.x * 32;

    if (tid < 32)       sidx[tid]      = src[ebase + tid];
    else if (tid < 64)  didx[tid - 32] = dst[ebase + tid - 32];
    __syncthreads();

    const int wave = tid >> 6, lane = tid & 63;
    const float2 bias1 = *(const float2*)(be1 + lane * 2);
    #pragma unroll
    for (int i = 0; i < 8; ++i) {
        int e = wave * 8 + i;
        int s = sidx[e], d = didx[e];
        float2 a = *(const float2*)(uv + (size_t)s * 256 + lane * 2);
        float2 b = *(const float2*)(uv + (size_t)d * 256 + 128 + lane * 2);
        float2 h;
        h.x = fmaxf(a.x + b.x + bias1.x, 0.f);
        h.y = fmaxf(a.y + b.y + bias1.y, 0.f);
        *(float2*)&H1[e][lane * 2] = h;
    }

    const int col_t = tid & 31;
    const int row_t = tid >> 5;

    float acc2[4][4] = {};
    for (int kb = 0; kb < 128; kb += 32) {
        __syncthreads();
        #pragma unroll
        for (int i = 0; i < 4; ++i) {
            int f = tid + i * 256;
            int r = f >> 5, c4 = (f & 31) << 2;
            *(float4*)&Ws[r][c4] = *(const float4*)(We2 + (size_t)(kb + r) * 128 + c4);
        }
        __syncthreads();
        #pragma unroll
        for (int k4 = 0; k4 < 8; ++k4) {
            float4 a[4], bb[4];
            #pragma unroll
            for (int i = 0; i < 4; ++i)
                a[i] = *(const float4*)&H1[row_t * 4 + i][kb + k4 * 4];
            #pragma unroll
            for (int kk = 0; kk < 4; ++kk)
                bb[kk] = *(const float4*)&Ws[k4 * 4 + kk][col_t * 4];
            const float* ap = reinterpret_cast<const float*>(a);
            const float* bp = reinterpret_cast<const float*>(bb);
            #pragma unroll
            for (int kk = 0; kk < 4; ++kk)
                #pragma unroll
                for (int i = 0; i < 4; ++i)
                    #pragma unroll
                    for (int j = 0; j < 4; ++j)
                        acc2[i][j] = fmaf(ap[i * 4 + kk], bp[kk * 4 + j], acc2[i][j]);
        }
    }

    const float4 be2v = *(const float4*)(be2 + col_t * 4);
    const float4 wd = last ? *(const float4*)(Wd + col_t * 4)
                           : make_float4(0.f, 0.f, 0.f, 0.f);
    #pragma unroll
    for (int i = 0; i < 4; ++i) {
        int e = ebase + row_t * 4 + i;
        float4 o;
        o.x = fmaxf(acc2[i][0] + be2v.x, 0.f);
        o.y = fmaxf(acc2[i][1] + be2v.y, 0.f);
        o.z = fmaxf(acc2[i][2] + be2v.z, 0.f);
        o.w = fmaxf(acc2[i][3] + be2v.w, 0.f);
        *(float4*)(xe + (size_t)e * 128 + col_t * 4) = o;
        if (last)
            red[row_t * 4 + i][col_t] =
                o.x * wd.x + o.y * wd.y + o.z * wd.z + o.w * wd.w;
    }
    if (last) {
        __syncthreads();
        if (tid < 32) {
            float s = 0.f;
            #pragma unroll
            for (int c = 0; c < 32; ++c) s += red[tid][c];
            preds[ebase + tid] = 1.f / (1.f + expf(-(s + bd[0])));
        }
    }
}

// ---------------------------------------------------------------------------
// Atomic-free scatter replacement: wave-per-node CSR gather-sum.
//   x2h[n][0:128]   = sum_{e: src[e]=n} xe[e]
//   x2h[n][128:256] = sum_{e: dst[e]=n} xe[e]
// ---------------------------------------------------------------------------
__global__ __launch_bounds__(256) void node_accum(
    const float* __restrict__ xe,
    const int* __restrict__ rps, const int* __restrict__ perms,
    const int* __restrict__ rpd, const int* __restrict__ permd,
    float* __restrict__ x2h)
{
    const int wave = threadIdx.x >> 6, lane = threadIdx.x & 63;
    const int nid = blockIdx.x * 4 + wave;
    if (nid >= N_NODES) return;

    float2 a = make_float2(0.f, 0.f);
    {
        int b0 = rps[nid];
        int e0 = (nid == N_NODES - 1) ? N_EDGES : rps[nid + 1];
        for (int i = b0; i < e0; ++i) {
            int e = perms[i];
            float2 v = *(const float2*)(xe + (size_t)e * 128 + lane * 2);
            a.x += v.x; a.y += v.y;
        }
    }
    *(float2*)(x2h + (size_t)nid * 256 + lane * 2) = a;

    float2 b = make_float2(0.f, 0.f);
    {
        int b0 = rpd[nid];
        int e0 = (nid == N_NODES - 1) ? N_EDGES : rpd[nid + 1];
        for (int i = b0; i < e0; ++i) {
            int e = permd[i];
            float2 v = *(const float2*)(xe + (size_t)e * 128 + lane * 2);
            b.x += v.x; b.y += v.y;
        }
    }
    *(float2*)(x2h + (size_t)nid * 256 + 128 + lane * 2) = b;
}

// ---------------------------------------------------------------------------
extern "C" void kernel_launch(void* const* d_in, const int* in_sizes, int n_in,
                              void* d_out, int out_size, void* d_ws, size_t ws_size,
                              hipStream_t stream)
{
    const float* inputs = (const float*)d_in[0];
    const float* W_n11  = (const float*)d_in[1];
    const float* b_n11  = (const float*)d_in[2];
    const float* W_n21  = (const float*)d_in[3];
    const float* b_n21  = (const float*)d_in[4];
    const float* W_n22  = (const float*)d_in[5];
    const float* b_n22  = (const float*)d_in[6];
    const float* W_e11  = (const float*)d_in[7];
    const float* b_e11  = (const float*)d_in[8];
    const float* W_e12  = (const float*)d_in[9];
    const float* b_e12  = (const float*)d_in[10];
    const float* W_dec  = (const float*)d_in[11];
    const float* b_dec  = (const float*)d_in[12];
    const int*   src    = (const int*)d_in[13];
    const int*   dst    = (const int*)d_in[14];

    // ws layout (~108.2 MB):
    //   buf [N,256]  -- time-shared: x2h (accum out / n21 in) and uv (uvgemm
    //                   out / edge in). Lifetimes proven disjoint per iter.
    //   Wcat [128,256] | rp_s[N] | rp_d[N] | cur_s[N] | cur_d[N]
    //   perm_s[E] | perm_d[E] | bsum[128]
    float* buf  = (float*)d_ws;
    float* Wcat = buf + (size_t)N_NODES * 256;
    int* rp_s   = (int*)(Wcat + 128 * 256);
    int* rp_d   = rp_s + N_NODES;
    int* cur_s  = rp_d + N_NODES;
    int* cur_d  = cur_s + N_NODES;
    int* perm_s = cur_d + N_NODES;
    int* perm_d = perm_s + N_EDGES;
    int* bsum_s = perm_d + N_EDGES;
    int* bsum_d = bsum_s + 128;

    float* x2h = buf;   // aliases by phase
    float* uv  = buf;

    float* preds = (float*)d_out;
    float* z     = preds + N_EDGES;         // [E,128] region of d_out

    // Z-region time-sharing: tmp/xh live only between n21 and uvgemm;
    // xe (full Z) lives only between edge_fused and node_accum. Disjoint.
    float* tmp = z;
    float* xh  = z + (size_t)N_NODES * 128;
    float* xe  = z;

    const int rowTiles  = (N_NODES + 63) / 64;     // 1563
    const int scanBlks  = (N_NODES + SCAN_CHUNK - 1) / SCAN_CHUNK;   // 98
    const int nodeBlks  = (N_NODES + 255) / 256;   // 391
    const int edgeBlks  = (N_EDGES + 255) / 256;   // 2344

    // ---- per-launch setup: weight repack + CSR build ----
    repack_We11<<<128, 256, 0, stream>>>(W_e11, Wcat);
    hipMemsetAsync(rp_s, 0, 2 * N_NODES * sizeof(int), stream);   // rp_s + rp_d
    edge_hist<<<edgeBlks, 256, 0, stream>>>(src, dst, rp_s, rp_d);
    scan_phase1<<<scanBlks, 256, 0, stream>>>(rp_s, bsum_s, N_NODES);
    scan_phase1<<<scanBlks, 256, 0, stream>>>(rp_d, bsum_d, N_NODES);
    scan_phase2<<<1, 64, 0, stream>>>(bsum_s, scanBlks);
    scan_phase2<<<1, 64, 0, stream>>>(bsum_d, scanBlks);
    scan_phase3<<<nodeBlks, 256, 0, stream>>>(rp_s, bsum_s, cur_s, N_NODES);
    scan_phase3<<<nodeBlks, 256, 0, stream>>>(rp_d, bsum_d, cur_d, N_NODES);
    edge_fill<<<edgeBlks, 256, 0, stream>>>(src, dst, cur_s, cur_d, perm_s, perm_d);

    // ---- node encoder: [N,64] -> [N,256] ----
    gemm_bias_relu<<<dim3(rowTiles, 4), 256, 0, stream>>>(
        inputs, W_n11, b_n11, x2h, N_NODES, 64, 256, 1);

    for (int it = 0; it < 3; ++it) {
        const int last = (it == 2);
        // node MLP: [N,256] -> [N,128] -> [N,128]
        gemm_bias_relu<<<dim3(rowTiles, 2), 256, 0, stream>>>(
            x2h, W_n21, b_n21, tmp, N_NODES, 256, 128, 1);
        gemm_bias_relu<<<dim3(rowTiles, 2), 256, 0, stream>>>(
            tmp, W_n22, b_n22, xh, N_NODES, 128, 128, 1);
        // factored edge layer 1, node side: uv = xh @ Wcat
        gemm_bias_relu<<<dim3(rowTiles, 4), 256, 0, stream>>>(
            xh, Wcat, nullptr, uv, N_NODES, 128, 256, 0);
        // edge MLP -> xe (plain stores; on last iter xe == z, + fused decoder)
        edge_fused<<<N_EDGES / 32, 256, 0, stream>>>(
            uv, src, dst, b_e11, W_e12, b_e12, W_dec, b_dec, xe, preds, last);
        // atomic-free scatter: CSR gather-sum (overwrites buf as x2h)
        if (!last)
            node_accum<<<(N_NODES + 3) / 4, 256, 0, stream>>>(
                xe, rp_s, perm_s, rp_d, perm_d, x2h);
    }
}

// Round 7
// 2044.900 us; speedup vs baseline: 2.6250x; 1.1793x over previous
//
#include <hip/hip_runtime.h>
#include <math.h>

#define N_NODES 100000
#define N_EDGES 600000
#define SCAN_CHUNK 1024

typedef __attribute__((ext_vector_type(8))) short bf16x8;
typedef __attribute__((ext_vector_type(4))) float f32x4;
typedef __attribute__((ext_vector_type(8))) unsigned short us8;

// float -> bf16 (RNE) bit trick; lo = bf16(x - hi) captures next 8 mantissa bits
__device__ __forceinline__ unsigned short f2bf(float x) {
    unsigned int u = __float_as_uint(x);
    u += 0x7FFFu + ((u >> 16) & 1u);
    return (unsigned short)(u >> 16);
}
__device__ __forceinline__ float bf2f(unsigned short h) {
    return __uint_as_float(((unsigned int)h) << 16);
}

// ---------------------------------------------------------------------------
// Split-bf16 MFMA GEMM: C[M,Nc] = act(A[M,K] @ W[K,Nc] + b)
// A fp32; W pre-transposed+split as WhT/WlT [Nc][K] bf16.
// A@W ~= Ah@Wh + Ah@Wl + Al@Wh  (drop Al@Wl, rel err ~2^-17 -> abs ~1e-3)
// BM=128, BN=128, BK=32; 256 thr = 4 waves (2x2), each wave 64x64 out
// (4x4 tiles of 16x16x32 MFMA). K%32==0, Nc%128==0, row-guard on M.
// Fragment layouts (verified m89/m92): A lane l: row=l&15, k=(l>>4)*8+j;
// B lane l: col=l&15, k=(l>>4)*8+j (k lane-contiguous via [Nc][K] transpose);
// D lane l: col=l&15, row=(l>>4)*4+reg.
// ---------------------------------------------------------------------------
__global__ __launch_bounds__(256) void gemm_mfma(
    const float* __restrict__ A,
    const unsigned short* __restrict__ WhT, const unsigned short* __restrict__ WlT,
    const float* __restrict__ b, float* __restrict__ C,
    int M, int K, int Nc, int act)
{
    // rows padded to 40 ushorts (80B = 20 banks): 16B-aligned frag reads,
    // 2-way bank aliasing max (free per m136)
    __shared__ __align__(16) unsigned short Ah[128][40], Al[128][40];
    __shared__ __align__(16) unsigned short Bh[128][40], Bl[128][40];

    const int tid  = threadIdx.x;
    const int wid  = tid >> 6, lane = tid & 63;
    const int wr   = wid >> 1, wc = wid & 1;        // wave grid 2x2
    const int lr   = lane & 15;                     // frag row (A) / col (B,D)
    const int lg   = lane >> 4;                     // k-octet group / D row-quad
    const int rowBase = blockIdx.x * 128;
    const int colBase = blockIdx.y * 128;

    f32x4 acc[4][4];
    #pragma unroll
    for (int i = 0; i < 4; ++i)
        #pragma unroll
        for (int j = 0; j < 4; ++j)
            acc[i][j] = (f32x4)(0.0f);

    for (int kb = 0; kb < K; kb += 32) {
        // ---- stage A tile [128][32]: fp32 load -> split -> LDS bf16 hi/lo ----
        #pragma unroll
        for (int i = 0; i < 4; ++i) {
            int v = tid + i * 256;           // 0..1023 float4s
            int row = v >> 3, c4 = (v & 7) << 2;
            int gr = rowBase + row;
            float4 a = make_float4(0.f, 0.f, 0.f, 0.f);
            if (gr < M) a = *(const float4*)(A + (size_t)gr * K + kb + c4);
            ushort4 vh, vl;
            vh.x = f2bf(a.x); vl.x = f2bf(a.x - bf2f(vh.x));
            vh.y = f2bf(a.y); vl.y = f2bf(a.y - bf2f(vh.y));
            vh.z = f2bf(a.z); vl.z = f2bf(a.z - bf2f(vh.z));
            vh.w = f2bf(a.w); vl.w = f2bf(a.w - bf2f(vh.w));
            *(ushort4*)&Ah[row][c4] = vh;
            *(ushort4*)&Al[row][c4] = vl;
        }
        // ---- stage B tile: WhT/WlT [col][32] bf16, direct copy (pre-split) ----
        #pragma unroll
        for (int i = 0; i < 2; ++i) {
            int u = tid + i * 256;           // 0..511 ushort8s
            int col = u >> 2, c8 = (u & 3) << 3;
            size_t goff = (size_t)(colBase + col) * K + kb + c8;
            *(us8*)&Bh[col][c8] = *(const us8*)(WhT + goff);
            *(us8*)&Bl[col][c8] = *(const us8*)(WlT + goff);
        }
        __syncthreads();

        // ---- fragments + MFMA ----
        bf16x8 fah[4], fal[4], fbh[4], fbl[4];
        #pragma unroll
        for (int mt = 0; mt < 4; ++mt) {
            int r = wr * 64 + mt * 16 + lr;
            fah[mt] = *(const bf16x8*)&Ah[r][lg * 8];
            fal[mt] = *(const bf16x8*)&Al[r][lg * 8];
        }
        #pragma unroll
        for (int nt = 0; nt < 4; ++nt) {
            int c = wc * 64 + nt * 16 + lr;
            fbh[nt] = *(const bf16x8*)&Bh[c][lg * 8];
            fbl[nt] = *(const bf16x8*)&Bl[c][lg * 8];
        }
        #pragma unroll
        for (int mt = 0; mt < 4; ++mt)
            #pragma unroll
            for (int nt = 0; nt < 4; ++nt) {
                acc[mt][nt] = __builtin_amdgcn_mfma_f32_16x16x32_bf16(
                    fah[mt], fbh[nt], acc[mt][nt], 0, 0, 0);
                acc[mt][nt] = __builtin_amdgcn_mfma_f32_16x16x32_bf16(
                    fah[mt], fbl[nt], acc[mt][nt], 0, 0, 0);
                acc[mt][nt] = __builtin_amdgcn_mfma_f32_16x16x32_bf16(
                    fal[mt], fbh[nt], acc[mt][nt], 0, 0, 0);
            }
        __syncthreads();
    }

    // ---- epilogue: D[row=(lg*4+q)][col=lr] per 16x16 tile ----
    #pragma unroll
    for (int nt = 0; nt < 4; ++nt) {
        int cg = colBase + wc * 64 + nt * 16 + lr;
        float bias = act ? b[cg] : 0.f;
        #pragma unroll
        for (int mt = 0; mt < 4; ++mt) {
            int r0 = rowBase + wr * 64 + mt * 16 + lg * 4;
            #pragma unroll
            for (int q = 0; q < 4; ++q) {
                int r = r0 + q;
                if (r < M) {
                    float v = acc[mt][nt][q] + bias;
                    if (act) v = fmaxf(v, 0.f);
                    C[(size_t)r * Nc + cg] = v;
                }
            }
        }
    }
}

// ---------------------------------------------------------------------------
// One-time weight repacks: W[K][Nc] -> WhT/WlT [Nc][K] bf16 split
// ---------------------------------------------------------------------------
__global__ __launch_bounds__(256) void repack_T_split(
    const float* __restrict__ W, unsigned short* __restrict__ WhT,
    unsigned short* __restrict__ WlT, int K, int Nc)
{
    int idx = blockIdx.x * 256 + threadIdx.x;
    if (idx >= K * Nc) return;
    int k = idx / Nc, c = idx % Nc;
    float x = W[idx];
    unsigned short h = f2bf(x);
    unsigned short l = f2bf(x - bf2f(h));
    WhT[(size_t)c * K + k] = h;
    WlT[(size_t)c * K + k] = l;
}

// W_e11 [256][128] -> WcatT [256][128] bf16 split, fused concat-factor:
//   Wcat[k][j] = (j<128) ? We11[k][j] : We11[128+k][j-128];  WcatT[j][k]=Wcat[k][j]
__global__ __launch_bounds__(256) void repack_we11_T_split(
    const float* __restrict__ We11, unsigned short* __restrict__ WhT,
    unsigned short* __restrict__ WlT)
{
    int idx = blockIdx.x * 256 + threadIdx.x;   // 0..32767
    if (idx >= 128 * 256) return;
    int k = idx >> 8, j = idx & 255;
    float x = (j < 128) ? We11[k * 128 + j] : We11[(128 + k) * 128 + (j - 128)];
    unsigned short h = f2bf(x);
    unsigned short l = f2bf(x - bf2f(h));
    WhT[(size_t)j * 128 + k] = h;
    WlT[(size_t)j * 128 + k] = l;
}

// ---------------------------------------------------------------------------
// CSR build: histogram -> in-place exclusive scan (3 phases) -> fill perm
// ---------------------------------------------------------------------------
__global__ __launch_bounds__(256) void edge_hist(
    const int* __restrict__ src, const int* __restrict__ dst,
    int* __restrict__ cs, int* __restrict__ cd)
{
    int e = blockIdx.x * 256 + threadIdx.x;
    if (e < N_EDGES) {
        atomicAdd(&cs[src[e]], 1);
        atomicAdd(&cd[dst[e]], 1);
    }
}

__global__ __launch_bounds__(256) void scan_phase1(
    int* __restrict__ a, int* __restrict__ bsum, int n)
{
    __shared__ int s[256];
    const int t = threadIdx.x;
    const int base = blockIdx.x * SCAN_CHUNK;
    int v[4], sum = 0;
    #pragma unroll
    for (int i = 0; i < 4; ++i) {
        int idx = base + t * 4 + i;
        v[i] = (idx < n) ? a[idx] : 0;
        sum += v[i];
    }
    s[t] = sum;
    __syncthreads();
    for (int off = 1; off < 256; off <<= 1) {
        int x = (t >= off) ? s[t - off] : 0;
        __syncthreads();
        s[t] += x;
        __syncthreads();
    }
    if (t == 255) bsum[blockIdx.x] = s[255];
    int run = s[t] - sum;
    #pragma unroll
    for (int i = 0; i < 4; ++i) {
        int idx = base + t * 4 + i;
        if (idx < n) a[idx] = run;
        run += v[i];
    }
}

__global__ void scan_phase2(int* __restrict__ bsum, int nb)
{
    if (threadIdx.x == 0 && blockIdx.x == 0) {
        int run = 0;
        for (int b = 0; b < nb; ++b) { int x = bsum[b]; bsum[b] = run; run += x; }
    }
}

__global__ __launch_bounds__(256) void scan_phase3(
    int* __restrict__ a, const int* __restrict__ bsum,
    int* __restrict__ cur, int n)
{
    int idx = blockIdx.x * 256 + threadIdx.x;
    if (idx < n) {
        int v = a[idx] + bsum[idx / SCAN_CHUNK];
        a[idx] = v;
        cur[idx] = v;
    }
}

__global__ __launch_bounds__(256) void edge_fill(
    const int* __restrict__ src, const int* __restrict__ dst,
    int* __restrict__ curs, int* __restrict__ curd,
    int* __restrict__ perms, int* __restrict__ permd)
{
    int e = blockIdx.x * 256 + threadIdx.x;
    if (e < N_EDGES) {
        int p1 = atomicAdd(&curs[src[e]], 1); perms[p1] = e;
        int p2 = atomicAdd(&curd[dst[e]], 1); permd[p2] = e;
    }
}

// ---------------------------------------------------------------------------
// Fused edge pipeline, 32 edges/block, split-bf16 MFMA layer 2:
//   h1 = relu(uv[src][0:128] + uv[dst][128:256] + b_e11)  (fp32, split to LDS)
//   h2 = relu(h1 @ W_e12 + b_e12)   via 3-product split-bf16 MFMA, K=128
//   xe[e] = h2;  if last: preds[e] = sigmoid(h2 . W_dec + b_dec)
// 4 waves: wave w -> cols w*32..+31 (2 col-tiles), rows 0..31 (2 row-tiles).
// Same fragment/staging patterns as gemm_mfma.
// ---------------------------------------------------------------------------
__global__ __launch_bounds__(256) void edge_fused_mfma(
    const float* __restrict__ uv,
    const int* __restrict__ src, const int* __restrict__ dst,
    const float* __restrict__ be1,
    const unsigned short* __restrict__ We2Th, const unsigned short* __restrict__ We2Tl,
    const float* __restrict__ be2,
    const float* __restrict__ Wd, const float* __restrict__ bd,
    float* __restrict__ xe, float* __restrict__ preds, int last)
{
    // H1 rows padded to 136 ushorts (272B = 17x16B): aligned, 2-way banks max
    __shared__ __align__(16) unsigned short H1h[32][136], H1l[32][136];
    __shared__ __align__(16) unsigned short Bh[128][40], Bl[128][40];
    __shared__ float red[32][65];
    __shared__ int   sidx[32], didx[32];

    const int tid   = threadIdx.x;
    const int ebase = blockIdx.x * 32;
    const int w     = tid >> 6, lane = tid & 63;
    const int lr    = lane & 15, lg = lane >> 4;

    if (tid < 32)       sidx[tid]      = src[ebase + tid];
    else if (tid < 64)  didx[tid - 32] = dst[ebase + tid - 32];
    __syncthreads();

    // ---- layer 1: gather u[src]+v[dst]+bias, relu, split-store to LDS ----
    const float2 bias1 = *(const float2*)(be1 + lane * 2);
    #pragma unroll
    for (int i = 0; i < 8; ++i) {
        int e = w * 8 + i;
        int s = sidx[e], d = didx[e];
        float2 a = *(const float2*)(uv + (size_t)s * 256 + lane * 2);
        float2 b = *(const float2*)(uv + (size_t)d * 256 + 128 + lane * 2);
        float hx = fmaxf(a.x + b.x + bias1.x, 0.f);
        float hy = fmaxf(a.y + b.y + bias1.y, 0.f);
        ushort2 vh, vl;
        vh.x = f2bf(hx); vl.x = f2bf(hx - bf2f(vh.x));
        vh.y = f2bf(hy); vl.y = f2bf(hy - bf2f(vh.y));
        *(ushort2*)&H1h[e][lane * 2] = vh;
        *(ushort2*)&H1l[e][lane * 2] = vl;
    }
    // (first in-loop __syncthreads covers H1 visibility)

    // ---- layer 2: 32x128 = (2 row-tiles) x (2 col-tiles per wave), K=128 ----
    f32x4 acc[2][2];
    #pragma unroll
    for (int i = 0; i < 2; ++i)
        #pragma unroll
        for (int j = 0; j < 2; ++j)
            acc[i][j] = (f32x4)(0.0f);

    for (int kb = 0; kb < 128; kb += 32) {
        #pragma unroll
        for (int i = 0; i < 2; ++i) {
            int u = tid + i * 256;           // 0..511 ushort8s
            int col = u >> 2, c8 = (u & 3) << 3;
            size_t goff = (size_t)col * 128 + kb + c8;
            *(us8*)&Bh[col][c8] = *(const us8*)(We2Th + goff);
            *(us8*)&Bl[col][c8] = *(const us8*)(We2Tl + goff);
        }
        __syncthreads();

        bf16x8 fah[2], fal[2], fbh[2], fbl[2];
        #pragma unroll
        for (int mt = 0; mt < 2; ++mt) {
            int r = mt * 16 + lr;
            fah[mt] = *(const bf16x8*)&H1h[r][kb + lg * 8];
            fal[mt] = *(const bf16x8*)&H1l[r][kb + lg * 8];
        }
        #pragma unroll
        for (int nt = 0; nt < 2; ++nt) {
            int c = w * 32 + nt * 16 + lr;
            fbh[nt] = *(const bf16x8*)&Bh[c][lg * 8];
            fbl[nt] = *(const bf16x8*)&Bl[c][lg * 8];
        }
        #pragma unroll
        for (int mt = 0; mt < 2; ++mt)
            #pragma unroll
            for (int nt = 0; nt < 2; ++nt) {
                acc[mt][nt] = __builtin_amdgcn_mfma_f32_16x16x32_bf16(
                    fah[mt], fbh[nt], acc[mt][nt], 0, 0, 0);
                acc[mt][nt] = __builtin_amdgcn_mfma_f32_16x16x32_bf16(
                    fah[mt], fbl[nt], acc[mt][nt], 0, 0, 0);
                acc[mt][nt] = __builtin_amdgcn_mfma_f32_16x16x32_bf16(
                    fal[mt], fbh[nt], acc[mt][nt], 0, 0, 0);
            }
        __syncthreads();
    }

    // ---- epilogue: bias+relu, store xe, optional fused decoder ----
    float partial[2][4] = {};          // per (mt,q), summed over nt
    #pragma unroll
    for (int nt = 0; nt < 2; ++nt) {
        int cg = w * 32 + nt * 16 + lr;
        float bias2 = be2[cg];
        float wdv = last ? Wd[cg] : 0.f;
        #pragma unroll
        for (int mt = 0; mt < 2; ++mt)
            #pragma unroll
            for (int q = 0; q < 4; ++q) {
                int r = mt * 16 + lg * 4 + q;
                float v = fmaxf(acc[mt][nt][q] + bias2, 0.f);
                xe[(size_t)(ebase + r) * 128 + cg] = v;
                partial[mt][q] += v * wdv;
            }
    }
    if (last) {
        #pragma unroll
        for (int mt = 0; mt < 2; ++mt)
            #pragma unroll
            for (int q = 0; q < 4; ++q)
                red[mt * 16 + lg * 4 + q][w * 16 + lr] = partial[mt][q];
        __syncthreads();
        if (tid < 32) {
            float s = 0.f;
            #pragma unroll
            for (int j = 0; j < 64; ++j) s += red[tid][j];
            preds[ebase + tid] = 1.f / (1.f + expf(-(s + bd[0])));
        }
    }
}

// ---------------------------------------------------------------------------
// Atomic-free scatter: wave-per-node CSR gather-sum (unchanged from r4)
// ---------------------------------------------------------------------------
__global__ __launch_bounds__(256) void node_accum(
    const float* __restrict__ xe,
    const int* __restrict__ rps, const int* __restrict__ perms,
    const int* __restrict__ rpd, const int* __restrict__ permd,
    float* __restrict__ x2h)
{
    const int wave = threadIdx.x >> 6, lane = threadIdx.x & 63;
    const int nid = blockIdx.x * 4 + wave;
    if (nid >= N_NODES) return;

    float2 a = make_float2(0.f, 0.f);
    {
        int b0 = rps[nid];
        int e0 = (nid == N_NODES - 1) ? N_EDGES : rps[nid + 1];
        for (int i = b0; i < e0; ++i) {
            int e = perms[i];
            float2 v = *(const float2*)(xe + (size_t)e * 128 + lane * 2);
            a.x += v.x; a.y += v.y;
        }
    }
    *(float2*)(x2h + (size_t)nid * 256 + lane * 2) = a;

    float2 b = make_float2(0.f, 0.f);
    {
        int b0 = rpd[nid];
        int e0 = (nid == N_NODES - 1) ? N_EDGES : rpd[nid + 1];
        for (int i = b0; i < e0; ++i) {
            int e = permd[i];
            float2 v = *(const float2*)(xe + (size_t)e * 128 + lane * 2);
            b.x += v.x; b.y += v.y;
        }
    }
    *(float2*)(x2h + (size_t)nid * 256 + 128 + lane * 2) = b;
}

// ---------------------------------------------------------------------------
extern "C" void kernel_launch(void* const* d_in, const int* in_sizes, int n_in,
                              void* d_out, int out_size, void* d_ws, size_t ws_size,
                              hipStream_t stream)
{
    const float* inputs = (const float*)d_in[0];
    const float* W_n11  = (const float*)d_in[1];
    const float* b_n11  = (const float*)d_in[2];
    const float* W_n21  = (const float*)d_in[3];
    const float* b_n21  = (const float*)d_in[4];
    const float* W_n22  = (const float*)d_in[5];
    const float* b_n22  = (const float*)d_in[6];
    const float* W_e11  = (const float*)d_in[7];
    const float* b_e11  = (const float*)d_in[8];
    const float* W_e12  = (const float*)d_in[9];
    const float* b_e12  = (const float*)d_in[10];
    const float* W_dec  = (const float*)d_in[11];
    const float* b_dec  = (const float*)d_in[12];
    const int*   src    = (const int*)d_in[13];
    const int*   dst    = (const int*)d_in[14];

    // ws layout (~104 MB):
    //  buf [N,256] fp32 (time-shared x2h / uv) | CSR ints | split weights (bf16)
    float* buf  = (float*)d_ws;
    int* rp_s   = (int*)(buf + (size_t)N_NODES * 256);
    int* rp_d   = rp_s + N_NODES;
    int* cur_s  = rp_d + N_NODES;
    int* cur_d  = cur_s + N_NODES;
    int* perm_s = cur_d + N_NODES;
    int* perm_d = perm_s + N_EDGES;
    int* bsum_s = perm_d + N_EDGES;
    int* bsum_d = bsum_s + 128;
    unsigned short* n11Th  = (unsigned short*)(bsum_d + 128);
    unsigned short* n11Tl  = n11Th + 64 * 256;
    unsigned short* n21Th  = n11Tl + 64 * 256;
    unsigned short* n21Tl  = n21Th + 256 * 128;
    unsigned short* n22Th  = n21Tl + 256 * 128;
    unsigned short* n22Tl  = n22Th + 128 * 128;
    unsigned short* wcatTh = n22Tl + 128 * 128;
    unsigned short* wcatTl = wcatTh + 256 * 128;
    unsigned short* e12Th  = wcatTl + 256 * 128;
    unsigned short* e12Tl  = e12Th + 128 * 128;

    float* x2h = buf;   // aliases by phase (lifetimes disjoint per iter)
    float* uv  = buf;

    float* preds = (float*)d_out;
    float* z     = preds + N_EDGES;         // [E,128] region of d_out

    // z-region time-sharing (disjoint lifetimes, same-stream ordering)
    float* tmp = z;
    float* xh  = z + (size_t)N_NODES * 128;
    float* xe  = z;

    const int mBlks    = (N_NODES + 127) / 128;   // 782
    const int scanBlks = (N_NODES + SCAN_CHUNK - 1) / SCAN_CHUNK;   // 98
    const int nodeBlks = (N_NODES + 255) / 256;
    const int edgeBlks = (N_EDGES + 255) / 256;

    // ---- per-launch setup: weight transpose+split, CSR build ----
    repack_T_split<<<(64 * 256 + 255) / 256, 256, 0, stream>>>(W_n11, n11Th, n11Tl, 64, 256);
    repack_T_split<<<(256 * 128 + 255) / 256, 256, 0, stream>>>(W_n21, n21Th, n21Tl, 256, 128);
    repack_T_split<<<(128 * 128 + 255) / 256, 256, 0, stream>>>(W_n22, n22Th, n22Tl, 128, 128);
    repack_T_split<<<(128 * 128 + 255) / 256, 256, 0, stream>>>(W_e12, e12Th, e12Tl, 128, 128);
    repack_we11_T_split<<<(128 * 256 + 255) / 256, 256, 0, stream>>>(W_e11, wcatTh, wcatTl);

    hipMemsetAsync(rp_s, 0, 2 * N_NODES * sizeof(int), stream);
    edge_hist<<<edgeBlks, 256, 0, stream>>>(src, dst, rp_s, rp_d);
    scan_phase1<<<scanBlks, 256, 0, stream>>>(rp_s, bsum_s, N_NODES);
    scan_phase1<<<scanBlks, 256, 0, stream>>>(rp_d, bsum_d, N_NODES);
    scan_phase2<<<1, 64, 0, stream>>>(bsum_s, scanBlks);
    scan_phase2<<<1, 64, 0, stream>>>(bsum_d, scanBlks);
    scan_phase3<<<nodeBlks, 256, 0, stream>>>(rp_s, bsum_s, cur_s, N_NODES);
    scan_phase3<<<nodeBlks, 256, 0, stream>>>(rp_d, bsum_d, cur_d, N_NODES);
    edge_fill<<<edgeBlks, 256, 0, stream>>>(src, dst, cur_s, cur_d, perm_s, perm_d);

    // ---- node encoder: [N,64] -> [N,256] ----
    gemm_mfma<<<dim3(mBlks, 2), 256, 0, stream>>>(
        inputs, n11Th, n11Tl, b_n11, x2h, N_NODES, 64, 256, 1);

    for (int it = 0; it < 3; ++it) {
        const int last = (it == 2);
        // node MLP: [N,256] -> [N,128] -> [N,128]
        gemm_mfma<<<dim3(mBlks, 1), 256, 0, stream>>>(
            x2h, n21Th, n21Tl, b_n21, tmp, N_NODES, 256, 128, 1);
        gemm_mfma<<<dim3(mBlks, 1), 256, 0, stream>>>(
            tmp, n22Th, n22Tl, b_n22, xh, N_NODES, 128, 128, 1);
        // factored edge layer 1, node side: uv = xh @ Wcat
        gemm_mfma<<<dim3(mBlks, 2), 256, 0, stream>>>(
            xh, wcatTh, wcatTl, nullptr, uv, N_NODES, 128, 256, 0);
        // edge MLP (MFMA layer 2) -> xe (on last iter xe == z, + fused decoder)
        edge_fused_mfma<<<N_EDGES / 32, 256, 0, stream>>>(
            uv, src, dst, b_e11, e12Th, e12Tl, b_e12, W_dec, b_dec,
            xe, preds, last);
        // atomic-free scatter: CSR gather-sum
        if (!last)
            node_accum<<<(N_NODES + 3) / 4, 256, 0, stream>>>(
                xe, rp_s, perm_s, rp_d, perm_d, x2h);
    }
}

// Round 8
// 1882.547 us; speedup vs baseline: 2.8514x; 1.0862x over previous
//
#include <hip/hip_runtime.h>
#include <math.h>

#define N_NODES 100000
#define N_EDGES 600000
#define SCAN_CHUNK 1024

typedef __attribute__((ext_vector_type(8))) short bf16x8;
typedef __attribute__((ext_vector_type(4))) float f32x4;
typedef __attribute__((ext_vector_type(8))) unsigned short us8;

// float -> bf16 (RNE) bit trick; lo = bf16(x - hi) captures next 8 mantissa bits
__device__ __forceinline__ unsigned short f2bf(float x) {
    unsigned int u = __float_as_uint(x);
    u += 0x7FFFu + ((u >> 16) & 1u);
    return (unsigned short)(u >> 16);
}
__device__ __forceinline__ float bf2f(unsigned short h) {
    return __uint_as_float(((unsigned int)h) << 16);
}

// ---------------------------------------------------------------------------
// Split-bf16 MFMA GEMM: C[M,Nc] = act(A[M,K] @ W[K,Nc] + b)   (validated r7)
// ---------------------------------------------------------------------------
__global__ __launch_bounds__(256) void gemm_mfma(
    const float* __restrict__ A,
    const unsigned short* __restrict__ WhT, const unsigned short* __restrict__ WlT,
    const float* __restrict__ b, float* __restrict__ C,
    int M, int K, int Nc, int act)
{
    __shared__ __align__(16) unsigned short Ah[128][40], Al[128][40];
    __shared__ __align__(16) unsigned short Bh[128][40], Bl[128][40];

    const int tid  = threadIdx.x;
    const int wid  = tid >> 6, lane = tid & 63;
    const int wr   = wid >> 1, wc = wid & 1;
    const int lr   = lane & 15;
    const int lg   = lane >> 4;
    const int rowBase = blockIdx.x * 128;
    const int colBase = blockIdx.y * 128;

    f32x4 acc[4][4];
    #pragma unroll
    for (int i = 0; i < 4; ++i)
        #pragma unroll
        for (int j = 0; j < 4; ++j)
            acc[i][j] = (f32x4)(0.0f);

    for (int kb = 0; kb < K; kb += 32) {
        #pragma unroll
        for (int i = 0; i < 4; ++i) {
            int v = tid + i * 256;
            int row = v >> 3, c4 = (v & 7) << 2;
            int gr = rowBase + row;
            float4 a = make_float4(0.f, 0.f, 0.f, 0.f);
            if (gr < M) a = *(const float4*)(A + (size_t)gr * K + kb + c4);
            ushort4 vh, vl;
            vh.x = f2bf(a.x); vl.x = f2bf(a.x - bf2f(vh.x));
            vh.y = f2bf(a.y); vl.y = f2bf(a.y - bf2f(vh.y));
            vh.z = f2bf(a.z); vl.z = f2bf(a.z - bf2f(vh.z));
            vh.w = f2bf(a.w); vl.w = f2bf(a.w - bf2f(vh.w));
            *(ushort4*)&Ah[row][c4] = vh;
            *(ushort4*)&Al[row][c4] = vl;
        }
        #pragma unroll
        for (int i = 0; i < 2; ++i) {
            int u = tid + i * 256;
            int col = u >> 2, c8 = (u & 3) << 3;
            size_t goff = (size_t)(colBase + col) * K + kb + c8;
            *(us8*)&Bh[col][c8] = *(const us8*)(WhT + goff);
            *(us8*)&Bl[col][c8] = *(const us8*)(WlT + goff);
        }
        __syncthreads();

        bf16x8 fah[4], fal[4], fbh[4], fbl[4];
        #pragma unroll
        for (int mt = 0; mt < 4; ++mt) {
            int r = wr * 64 + mt * 16 + lr;
            fah[mt] = *(const bf16x8*)&Ah[r][lg * 8];
            fal[mt] = *(const bf16x8*)&Al[r][lg * 8];
        }
        #pragma unroll
        for (int nt = 0; nt < 4; ++nt) {
            int c = wc * 64 + nt * 16 + lr;
            fbh[nt] = *(const bf16x8*)&Bh[c][lg * 8];
            fbl[nt] = *(const bf16x8*)&Bl[c][lg * 8];
        }
        #pragma unroll
        for (int mt = 0; mt < 4; ++mt)
            #pragma unroll
            for (int nt = 0; nt < 4; ++nt) {
                acc[mt][nt] = __builtin_amdgcn_mfma_f32_16x16x32_bf16(
                    fah[mt], fbh[nt], acc[mt][nt], 0, 0, 0);
                acc[mt][nt] = __builtin_amdgcn_mfma_f32_16x16x32_bf16(
                    fah[mt], fbl[nt], acc[mt][nt], 0, 0, 0);
                acc[mt][nt] = __builtin_amdgcn_mfma_f32_16x16x32_bf16(
                    fal[mt], fbh[nt], acc[mt][nt], 0, 0, 0);
            }
        __syncthreads();
    }

    #pragma unroll
    for (int nt = 0; nt < 4; ++nt) {
        int cg = colBase + wc * 64 + nt * 16 + lr;
        float bias = act ? b[cg] : 0.f;
        #pragma unroll
        for (int mt = 0; mt < 4; ++mt) {
            int r0 = rowBase + wr * 64 + mt * 16 + lg * 4;
            #pragma unroll
            for (int q = 0; q < 4; ++q) {
                int r = r0 + q;
                if (r < M) {
                    float v = acc[mt][nt][q] + bias;
                    if (act) v = fmaxf(v, 0.f);
                    C[(size_t)r * Nc + cg] = v;
                }
            }
        }
    }
}

// ---------------------------------------------------------------------------
// One-time weight repacks (validated r7)
// ---------------------------------------------------------------------------
__global__ __launch_bounds__(256) void repack_T_split(
    const float* __restrict__ W, unsigned short* __restrict__ WhT,
    unsigned short* __restrict__ WlT, int K, int Nc)
{
    int idx = blockIdx.x * 256 + threadIdx.x;
    if (idx >= K * Nc) return;
    int k = idx / Nc, c = idx % Nc;
    float x = W[idx];
    unsigned short h = f2bf(x);
    unsigned short l = f2bf(x - bf2f(h));
    WhT[(size_t)c * K + k] = h;
    WlT[(size_t)c * K + k] = l;
}

__global__ __launch_bounds__(256) void repack_we11_T_split(
    const float* __restrict__ We11, unsigned short* __restrict__ WhT,
    unsigned short* __restrict__ WlT)
{
    int idx = blockIdx.x * 256 + threadIdx.x;
    if (idx >= 128 * 256) return;
    int k = idx >> 8, j = idx & 255;
    float x = (j < 128) ? We11[k * 128 + j] : We11[(128 + k) * 128 + (j - 128)];
    unsigned short h = f2bf(x);
    unsigned short l = f2bf(x - bf2f(h));
    WhT[(size_t)j * 128 + k] = h;
    WlT[(size_t)j * 128 + k] = l;
}

// ---------------------------------------------------------------------------
// CSR build: histogram -> exclusive scan -> fill perm -> sorted index arrays
// ---------------------------------------------------------------------------
__global__ __launch_bounds__(256) void edge_hist(
    const int* __restrict__ src, const int* __restrict__ dst,
    int* __restrict__ cs, int* __restrict__ cd)
{
    int e = blockIdx.x * 256 + threadIdx.x;
    if (e < N_EDGES) {
        atomicAdd(&cs[src[e]], 1);
        atomicAdd(&cd[dst[e]], 1);
    }
}

__global__ __launch_bounds__(256) void scan_phase1(
    int* __restrict__ a, int* __restrict__ bsum, int n)
{
    __shared__ int s[256];
    const int t = threadIdx.x;
    const int base = blockIdx.x * SCAN_CHUNK;
    int v[4], sum = 0;
    #pragma unroll
    for (int i = 0; i < 4; ++i) {
        int idx = base + t * 4 + i;
        v[i] = (idx < n) ? a[idx] : 0;
        sum += v[i];
    }
    s[t] = sum;
    __syncthreads();
    for (int off = 1; off < 256; off <<= 1) {
        int x = (t >= off) ? s[t - off] : 0;
        __syncthreads();
        s[t] += x;
        __syncthreads();
    }
    if (t == 255) bsum[blockIdx.x] = s[255];
    int run = s[t] - sum;
    #pragma unroll
    for (int i = 0; i < 4; ++i) {
        int idx = base + t * 4 + i;
        if (idx < n) a[idx] = run;
        run += v[i];
    }
}

__global__ void scan_phase2(int* __restrict__ bsum, int nb)
{
    if (threadIdx.x == 0 && blockIdx.x == 0) {
        int run = 0;
        for (int b = 0; b < nb; ++b) { int x = bsum[b]; bsum[b] = run; run += x; }
    }
}

__global__ __launch_bounds__(256) void scan_phase3(
    int* __restrict__ a, const int* __restrict__ bsum,
    int* __restrict__ cur, int n)
{
    int idx = blockIdx.x * 256 + threadIdx.x;
    if (idx < n) {
        int v = a[idx] + bsum[idx / SCAN_CHUNK];
        a[idx] = v;
        cur[idx] = v;
    }
}

__global__ __launch_bounds__(256) void edge_fill(
    const int* __restrict__ src, const int* __restrict__ dst,
    int* __restrict__ curs, int* __restrict__ curd,
    int* __restrict__ perms, int* __restrict__ permd)
{
    int e = blockIdx.x * 256 + threadIdx.x;
    if (e < N_EDGES) {
        int p1 = atomicAdd(&curs[src[e]], 1); perms[p1] = e;
        int p2 = atomicAdd(&curd[dst[e]], 1); permd[p2] = e;
    }
}

// ssrc[j]=src[perm_s[j]], sdst[j]=dst[perm_s[j]], ipos[perm_s[j]]=j
__global__ __launch_bounds__(256) void build_sorted(
    const int* __restrict__ src, const int* __restrict__ dst,
    const int* __restrict__ perms,
    int* __restrict__ ssrc, int* __restrict__ sdst, int* __restrict__ ipos)
{
    int j = blockIdx.x * 256 + threadIdx.x;
    if (j < N_EDGES) {
        int e = perms[j];
        ssrc[j] = src[e];
        sdst[j] = dst[e];
        ipos[e] = j;
    }
}

// pd2[i] = sorted-position of permd[i]  (dst-list -> xe row index)
__global__ __launch_bounds__(256) void build_pd2(
    const int* __restrict__ permd, const int* __restrict__ ipos,
    int* __restrict__ pd2)
{
    int i = blockIdx.x * 256 + threadIdx.x;
    if (i < N_EDGES) pd2[i] = ipos[permd[i]];
}

// ---------------------------------------------------------------------------
// Fused edge pipeline, 32 edges/block, split-bf16 MFMA layer 2 (validated r7).
// Index arrays decide processing order: (ssrc,sdst) = src-sorted for scatter
// iters (xe row j holds edge perm_s[j]); (src,dst) = natural for last iter.
// ---------------------------------------------------------------------------
__global__ __launch_bounds__(256) void edge_fused_mfma(
    const float* __restrict__ uv,
    const int* __restrict__ eS, const int* __restrict__ eD,
    const float* __restrict__ be1,
    const unsigned short* __restrict__ We2Th, const unsigned short* __restrict__ We2Tl,
    const float* __restrict__ be2,
    const float* __restrict__ Wd, const float* __restrict__ bd,
    float* __restrict__ xe, float* __restrict__ preds, int last)
{
    __shared__ __align__(16) unsigned short H1h[32][136], H1l[32][136];
    __shared__ __align__(16) unsigned short Bh[128][40], Bl[128][40];
    __shared__ float red[32][65];
    __shared__ int   sidx[32], didx[32];

    const int tid   = threadIdx.x;
    const int ebase = blockIdx.x * 32;
    const int w     = tid >> 6, lane = tid & 63;
    const int lr    = lane & 15, lg = lane >> 4;

    if (tid < 32)       sidx[tid]      = eS[ebase + tid];
    else if (tid < 64)  didx[tid - 32] = eD[ebase + tid - 32];
    __syncthreads();

    const float2 bias1 = *(const float2*)(be1 + lane * 2);
    #pragma unroll
    for (int i = 0; i < 8; ++i) {
        int e = w * 8 + i;
        int s = sidx[e], d = didx[e];
        float2 a = *(const float2*)(uv + (size_t)s * 256 + lane * 2);
        float2 b = *(const float2*)(uv + (size_t)d * 256 + 128 + lane * 2);
        float hx = fmaxf(a.x + b.x + bias1.x, 0.f);
        float hy = fmaxf(a.y + b.y + bias1.y, 0.f);
        ushort2 vh, vl;
        vh.x = f2bf(hx); vl.x = f2bf(hx - bf2f(vh.x));
        vh.y = f2bf(hy); vl.y = f2bf(hy - bf2f(vh.y));
        *(ushort2*)&H1h[e][lane * 2] = vh;
        *(ushort2*)&H1l[e][lane * 2] = vl;
    }

    f32x4 acc[2][2];
    #pragma unroll
    for (int i = 0; i < 2; ++i)
        #pragma unroll
        for (int j = 0; j < 2; ++j)
            acc[i][j] = (f32x4)(0.0f);

    for (int kb = 0; kb < 128; kb += 32) {
        #pragma unroll
        for (int i = 0; i < 2; ++i) {
            int u = tid + i * 256;
            int col = u >> 2, c8 = (u & 3) << 3;
            size_t goff = (size_t)col * 128 + kb + c8;
            *(us8*)&Bh[col][c8] = *(const us8*)(We2Th + goff);
            *(us8*)&Bl[col][c8] = *(const us8*)(We2Tl + goff);
        }
        __syncthreads();

        bf16x8 fah[2], fal[2], fbh[2], fbl[2];
        #pragma unroll
        for (int mt = 0; mt < 2; ++mt) {
            int r = mt * 16 + lr;
            fah[mt] = *(const bf16x8*)&H1h[r][kb + lg * 8];
            fal[mt] = *(const bf16x8*)&H1l[r][kb + lg * 8];
        }
        #pragma unroll
        for (int nt = 0; nt < 2; ++nt) {
            int c = w * 32 + nt * 16 + lr;
            fbh[nt] = *(const bf16x8*)&Bh[c][lg * 8];
            fbl[nt] = *(const bf16x8*)&Bl[c][lg * 8];
        }
        #pragma unroll
        for (int mt = 0; mt < 2; ++mt)
            #pragma unroll
            for (int nt = 0; nt < 2; ++nt) {
                acc[mt][nt] = __builtin_amdgcn_mfma_f32_16x16x32_bf16(
                    fah[mt], fbh[nt], acc[mt][nt], 0, 0, 0);
                acc[mt][nt] = __builtin_amdgcn_mfma_f32_16x16x32_bf16(
                    fah[mt], fbl[nt], acc[mt][nt], 0, 0, 0);
                acc[mt][nt] = __builtin_amdgcn_mfma_f32_16x16x32_bf16(
                    fal[mt], fbh[nt], acc[mt][nt], 0, 0, 0);
            }
        __syncthreads();
    }

    float partial[2][4] = {};
    #pragma unroll
    for (int nt = 0; nt < 2; ++nt) {
        int cg = w * 32 + nt * 16 + lr;
        float bias2 = be2[cg];
        float wdv = last ? Wd[cg] : 0.f;
        #pragma unroll
        for (int mt = 0; mt < 2; ++mt)
            #pragma unroll
            for (int q = 0; q < 4; ++q) {
                int r = mt * 16 + lg * 4 + q;
                float v = fmaxf(acc[mt][nt][q] + bias2, 0.f);
                xe[(size_t)(ebase + r) * 128 + cg] = v;
                partial[mt][q] += v * wdv;
            }
    }
    if (last) {
        #pragma unroll
        for (int mt = 0; mt < 2; ++mt)
            #pragma unroll
            for (int q = 0; q < 4; ++q)
                red[mt * 16 + lg * 4 + q][w * 16 + lr] = partial[mt][q];
        __syncthreads();
        if (tid < 32) {
            float s = 0.f;
            #pragma unroll
            for (int j = 0; j < 64; ++j) s += red[tid][j];
            preds[ebase + tid] = 1.f / (1.f + expf(-(s + bd[0])));
        }
    }
}

// ---------------------------------------------------------------------------
// Atomic-free scatter, v2: src-half is a CONTIGUOUS streaming sum of xe rows
// [rps[n], rps[n+1]) (xe is src-sorted); dst-half gathers rows pd2[i].
// 4-deep pipeline: 2 sequential + 2 indexed 512B row reads in flight.
// ---------------------------------------------------------------------------
__global__ __launch_bounds__(256) void node_accum(
    const float* __restrict__ xe,
    const int* __restrict__ rps,
    const int* __restrict__ rpd, const int* __restrict__ pd2,
    float* __restrict__ x2h)
{
    const int wave = threadIdx.x >> 6, lane = threadIdx.x & 63;
    const int nid = blockIdx.x * 4 + wave;
    if (nid >= N_NODES) return;
    const int c = lane * 2;

    const int s0 = rps[nid];
    const int s1 = (nid == N_NODES - 1) ? N_EDGES : rps[nid + 1];
    const int d0 = rpd[nid];
    const int d1 = (nid == N_NODES - 1) ? N_EDGES : rpd[nid + 1];

    float2 a = make_float2(0.f, 0.f), b = make_float2(0.f, 0.f);
    int is = s0, id = d0;

    while (is + 2 <= s1 && id + 2 <= d1) {
        float2 v0 = *(const float2*)(xe + (size_t)is * 128 + c);
        float2 v1 = *(const float2*)(xe + (size_t)(is + 1) * 128 + c);
        int f0 = pd2[id], f1 = pd2[id + 1];
        float2 w0 = *(const float2*)(xe + (size_t)f0 * 128 + c);
        float2 w1 = *(const float2*)(xe + (size_t)f1 * 128 + c);
        a.x += v0.x + v1.x; a.y += v0.y + v1.y;
        b.x += w0.x + w1.x; b.y += w0.y + w1.y;
        is += 2; id += 2;
    }
    while (is < s1) {
        float2 v = *(const float2*)(xe + (size_t)is * 128 + c);
        a.x += v.x; a.y += v.y; ++is;
    }
    while (id < d1) {
        int f = pd2[id];
        float2 w = *(const float2*)(xe + (size_t)f * 128 + c);
        b.x += w.x; b.y += w.y; ++id;
    }

    *(float2*)(x2h + (size_t)nid * 256 + c) = a;
    *(float2*)(x2h + (size_t)nid * 256 + 128 + c) = b;
}

// ---------------------------------------------------------------------------
extern "C" void kernel_launch(void* const* d_in, const int* in_sizes, int n_in,
                              void* d_out, int out_size, void* d_ws, size_t ws_size,
                              hipStream_t stream)
{
    const float* inputs = (const float*)d_in[0];
    const float* W_n11  = (const float*)d_in[1];
    const float* b_n11  = (const float*)d_in[2];
    const float* W_n21  = (const float*)d_in[3];
    const float* b_n21  = (const float*)d_in[4];
    const float* W_n22  = (const float*)d_in[5];
    const float* b_n22  = (const float*)d_in[6];
    const float* W_e11  = (const float*)d_in[7];
    const float* b_e11  = (const float*)d_in[8];
    const float* W_e12  = (const float*)d_in[9];
    const float* b_e12  = (const float*)d_in[10];
    const float* W_dec  = (const float*)d_in[11];
    const float* b_dec  = (const float*)d_in[12];
    const int*   src    = (const int*)d_in[13];
    const int*   dst    = (const int*)d_in[14];

    // ws layout (~114 MB): buf [N,256] fp32 | CSR ints | sorted idx | weights
    float* buf  = (float*)d_ws;
    int* rp_s   = (int*)(buf + (size_t)N_NODES * 256);
    int* rp_d   = rp_s + N_NODES;
    int* cur_s  = rp_d + N_NODES;
    int* cur_d  = cur_s + N_NODES;
    int* perm_s = cur_d + N_NODES;
    int* perm_d = perm_s + N_EDGES;
    int* bsum_s = perm_d + N_EDGES;
    int* bsum_d = bsum_s + 128;
    int* ssrc   = bsum_d + 128;
    int* sdst   = ssrc + N_EDGES;
    int* ipos   = sdst + N_EDGES;
    int* pd2    = ipos + N_EDGES;
    unsigned short* n11Th  = (unsigned short*)(pd2 + N_EDGES);
    unsigned short* n11Tl  = n11Th + 64 * 256;
    unsigned short* n21Th  = n11Tl + 64 * 256;
    unsigned short* n21Tl  = n21Th + 256 * 128;
    unsigned short* n22Th  = n21Tl + 256 * 128;
    unsigned short* n22Tl  = n22Th + 128 * 128;
    unsigned short* wcatTh = n22Tl + 128 * 128;
    unsigned short* wcatTl = wcatTh + 256 * 128;
    unsigned short* e12Th  = wcatTl + 256 * 128;
    unsigned short* e12Tl  = e12Th + 128 * 128;

    float* x2h = buf;   // aliases by phase (lifetimes disjoint per iter)
    float* uv  = buf;

    float* preds = (float*)d_out;
    float* z     = preds + N_EDGES;         // [E,128] region of d_out

    float* tmp = z;
    float* xh  = z + (size_t)N_NODES * 128;
    float* xe  = z;

    const int mBlks    = (N_NODES + 127) / 128;
    const int scanBlks = (N_NODES + SCAN_CHUNK - 1) / SCAN_CHUNK;
    const int nodeBlks = (N_NODES + 255) / 256;
    const int edgeBlks = (N_EDGES + 255) / 256;

    // ---- per-launch setup ----
    repack_T_split<<<(64 * 256 + 255) / 256, 256, 0, stream>>>(W_n11, n11Th, n11Tl, 64, 256);
    repack_T_split<<<(256 * 128 + 255) / 256, 256, 0, stream>>>(W_n21, n21Th, n21Tl, 256, 128);
    repack_T_split<<<(128 * 128 + 255) / 256, 256, 0, stream>>>(W_n22, n22Th, n22Tl, 128, 128);
    repack_T_split<<<(128 * 128 + 255) / 256, 256, 0, stream>>>(W_e12, e12Th, e12Tl, 128, 128);
    repack_we11_T_split<<<(128 * 256 + 255) / 256, 256, 0, stream>>>(W_e11, wcatTh, wcatTl);

    hipMemsetAsync(rp_s, 0, 2 * N_NODES * sizeof(int), stream);
    edge_hist<<<edgeBlks, 256, 0, stream>>>(src, dst, rp_s, rp_d);
    scan_phase1<<<scanBlks, 256, 0, stream>>>(rp_s, bsum_s, N_NODES);
    scan_phase1<<<scanBlks, 256, 0, stream>>>(rp_d, bsum_d, N_NODES);
    scan_phase2<<<1, 64, 0, stream>>>(bsum_s, scanBlks);
    scan_phase2<<<1, 64, 0, stream>>>(bsum_d, scanBlks);
    scan_phase3<<<nodeBlks, 256, 0, stream>>>(rp_s, bsum_s, cur_s, N_NODES);
    scan_phase3<<<nodeBlks, 256, 0, stream>>>(rp_d, bsum_d, cur_d, N_NODES);
    edge_fill<<<edgeBlks, 256, 0, stream>>>(src, dst, cur_s, cur_d, perm_s, perm_d);
    build_sorted<<<edgeBlks, 256, 0, stream>>>(src, dst, perm_s, ssrc, sdst, ipos);
    build_pd2<<<edgeBlks, 256, 0, stream>>>(perm_d, ipos, pd2);

    // ---- node encoder: [N,64] -> [N,256] ----
    gemm_mfma<<<dim3(mBlks, 2), 256, 0, stream>>>(
        inputs, n11Th, n11Tl, b_n11, x2h, N_NODES, 64, 256, 1);

    for (int it = 0; it < 3; ++it) {
        const int last = (it == 2);
        gemm_mfma<<<dim3(mBlks, 1), 256, 0, stream>>>(
            x2h, n21Th, n21Tl, b_n21, tmp, N_NODES, 256, 128, 1);
        gemm_mfma<<<dim3(mBlks, 1), 256, 0, stream>>>(
            tmp, n22Th, n22Tl, b_n22, xh, N_NODES, 128, 128, 1);
        gemm_mfma<<<dim3(mBlks, 2), 256, 0, stream>>>(
            xh, wcatTh, wcatTl, nullptr, uv, N_NODES, 128, 256, 0);
        // scatter iters process edges in src-sorted order (xe row j = edge
        // perm_s[j]); last iter uses natural order so xe == z layout.
        edge_fused_mfma<<<N_EDGES / 32, 256, 0, stream>>>(
            uv, last ? src : ssrc, last ? dst : sdst, b_e11,
            e12Th, e12Tl, b_e12, W_dec, b_dec, xe, preds, last);
        if (!last)
            node_accum<<<(N_NODES + 3) / 4, 256, 0, stream>>>(
                xe, rp_s, rp_d, pd2, x2h);
    }
}

// Round 10
// 1822.979 us; speedup vs baseline: 2.9446x; 1.0327x over previous
//
#include <hip/hip_runtime.h>
#include <math.h>

#define N_NODES 100000
#define N_EDGES 600000
#define SCAN_CHUNK 1024

typedef __attribute__((ext_vector_type(8))) short bf16x8;
typedef __attribute__((ext_vector_type(4))) float f32x4;
typedef __attribute__((ext_vector_type(8))) unsigned short us8;

// float -> bf16 (RNE) bit trick; lo = bf16(x - hi) captures next 8 mantissa bits
__device__ __forceinline__ unsigned short f2bf(float x) {
    unsigned int u = __float_as_uint(x);
    u += 0x7FFFu + ((u >> 16) & 1u);
    return (unsigned short)(u >> 16);
}
__device__ __forceinline__ float bf2f(unsigned short h) {
    return __uint_as_float(((unsigned int)h) << 16);
}

// ---------------------------------------------------------------------------
// Split-bf16 MFMA GEMM (validated r7/r8) + T14 prefetch: next K-slab's global
// loads issue into regs BEFORE current slab's MFMA; LDS write after barrier.
// ---------------------------------------------------------------------------
__global__ __launch_bounds__(256) void gemm_mfma(
    const float* __restrict__ A,
    const unsigned short* __restrict__ WhT, const unsigned short* __restrict__ WlT,
    const float* __restrict__ b, float* __restrict__ C,
    int M, int K, int Nc, int act)
{
    __shared__ __align__(16) unsigned short Ah[128][40], Al[128][40];
    __shared__ __align__(16) unsigned short Bh[128][40], Bl[128][40];

    const int tid  = threadIdx.x;
    const int wid  = tid >> 6, lane = tid & 63;
    const int wr   = wid >> 1, wc = wid & 1;
    const int lr   = lane & 15;
    const int lg   = lane >> 4;
    const int rowBase = blockIdx.x * 128;
    const int colBase = blockIdx.y * 128;

    float4 pa[4];
    us8 pbh[2], pbl[2];

    auto loadTiles = [&](int kb) {
        #pragma unroll
        for (int i = 0; i < 4; ++i) {
            int v = tid + i * 256;
            int row = v >> 3, c4 = (v & 7) << 2;
            int gr = rowBase + row;
            pa[i] = make_float4(0.f, 0.f, 0.f, 0.f);
            if (gr < M) pa[i] = *(const float4*)(A + (size_t)gr * K + kb + c4);
        }
        #pragma unroll
        for (int i = 0; i < 2; ++i) {
            int u = tid + i * 256;
            int col = u >> 2, c8 = (u & 3) << 3;
            size_t goff = (size_t)(colBase + col) * K + kb + c8;
            pbh[i] = *(const us8*)(WhT + goff);
            pbl[i] = *(const us8*)(WlT + goff);
        }
    };
    auto writeTiles = [&]() {
        #pragma unroll
        for (int i = 0; i < 4; ++i) {
            int v = tid + i * 256;
            int row = v >> 3, c4 = (v & 7) << 2;
            float4 a = pa[i];
            ushort4 vh, vl;
            vh.x = f2bf(a.x); vl.x = f2bf(a.x - bf2f(vh.x));
            vh.y = f2bf(a.y); vl.y = f2bf(a.y - bf2f(vh.y));
            vh.z = f2bf(a.z); vl.z = f2bf(a.z - bf2f(vh.z));
            vh.w = f2bf(a.w); vl.w = f2bf(a.w - bf2f(vh.w));
            *(ushort4*)&Ah[row][c4] = vh;
            *(ushort4*)&Al[row][c4] = vl;
        }
        #pragma unroll
        for (int i = 0; i < 2; ++i) {
            int u = tid + i * 256;
            int col = u >> 2, c8 = (u & 3) << 3;
            *(us8*)&Bh[col][c8] = pbh[i];
            *(us8*)&Bl[col][c8] = pbl[i];
        }
    };

    f32x4 acc[4][4];
    #pragma unroll
    for (int i = 0; i < 4; ++i)
        #pragma unroll
        for (int j = 0; j < 4; ++j)
            acc[i][j] = (f32x4)(0.0f);

    loadTiles(0);
    writeTiles();
    __syncthreads();

    for (int kb = 0; kb < K; kb += 32) {
        const bool more = (kb + 32) < K;
        if (more) loadTiles(kb + 32);     // in flight during ds reads + MFMA

        bf16x8 fah[4], fal[4], fbh[4], fbl[4];
        #pragma unroll
        for (int mt = 0; mt < 4; ++mt) {
            int r = wr * 64 + mt * 16 + lr;
            fah[mt] = *(const bf16x8*)&Ah[r][lg * 8];
            fal[mt] = *(const bf16x8*)&Al[r][lg * 8];
        }
        #pragma unroll
        for (int nt = 0; nt < 4; ++nt) {
            int c = wc * 64 + nt * 16 + lr;
            fbh[nt] = *(const bf16x8*)&Bh[c][lg * 8];
            fbl[nt] = *(const bf16x8*)&Bl[c][lg * 8];
        }
        #pragma unroll
        for (int mt = 0; mt < 4; ++mt)
            #pragma unroll
            for (int nt = 0; nt < 4; ++nt) {
                acc[mt][nt] = __builtin_amdgcn_mfma_f32_16x16x32_bf16(
                    fah[mt], fbh[nt], acc[mt][nt], 0, 0, 0);
                acc[mt][nt] = __builtin_amdgcn_mfma_f32_16x16x32_bf16(
                    fah[mt], fbl[nt], acc[mt][nt], 0, 0, 0);
                acc[mt][nt] = __builtin_amdgcn_mfma_f32_16x16x32_bf16(
                    fal[mt], fbh[nt], acc[mt][nt], 0, 0, 0);
            }
        __syncthreads();
        if (more) {
            writeTiles();
            __syncthreads();
        }
    }

    #pragma unroll
    for (int nt = 0; nt < 4; ++nt) {
        int cg = colBase + wc * 64 + nt * 16 + lr;
        float bias = act ? b[cg] : 0.f;
        #pragma unroll
        for (int mt = 0; mt < 4; ++mt) {
            int r0 = rowBase + wr * 64 + mt * 16 + lg * 4;
            #pragma unroll
            for (int q = 0; q < 4; ++q) {
                int r = r0 + q;
                if (r < M) {
                    float v = acc[mt][nt][q] + bias;
                    if (act) v = fmaxf(v, 0.f);
                    C[(size_t)r * Nc + cg] = v;
                }
            }
        }
    }
}

// ---------------------------------------------------------------------------
// One-time weight repacks (validated r7)
// ---------------------------------------------------------------------------
__global__ __launch_bounds__(256) void repack_T_split(
    const float* __restrict__ W, unsigned short* __restrict__ WhT,
    unsigned short* __restrict__ WlT, int K, int Nc)
{
    int idx = blockIdx.x * 256 + threadIdx.x;
    if (idx >= K * Nc) return;
    int k = idx / Nc, c = idx % Nc;
    float x = W[idx];
    unsigned short h = f2bf(x);
    unsigned short l = f2bf(x - bf2f(h));
    WhT[(size_t)c * K + k] = h;
    WlT[(size_t)c * K + k] = l;
}

__global__ __launch_bounds__(256) void repack_we11_T_split(
    const float* __restrict__ We11, unsigned short* __restrict__ WhT,
    unsigned short* __restrict__ WlT)
{
    int idx = blockIdx.x * 256 + threadIdx.x;
    if (idx >= 128 * 256) return;
    int k = idx >> 8, j = idx & 255;
    float x = (j < 128) ? We11[k * 128 + j] : We11[(128 + k) * 128 + (j - 128)];
    unsigned short h = f2bf(x);
    unsigned short l = f2bf(x - bf2f(h));
    WhT[(size_t)j * 128 + k] = h;
    WlT[(size_t)j * 128 + k] = l;
}

// ---------------------------------------------------------------------------
// CSR build: histogram -> exclusive scan -> fill perm -> sorted index arrays
// ---------------------------------------------------------------------------
__global__ __launch_bounds__(256) void edge_hist(
    const int* __restrict__ src, const int* __restrict__ dst,
    int* __restrict__ cs, int* __restrict__ cd)
{
    int e = blockIdx.x * 256 + threadIdx.x;
    if (e < N_EDGES) {
        atomicAdd(&cs[src[e]], 1);
        atomicAdd(&cd[dst[e]], 1);
    }
}

__global__ __launch_bounds__(256) void scan_phase1(
    int* __restrict__ a, int* __restrict__ bsum, int n)
{
    __shared__ int s[256];
    const int t = threadIdx.x;
    const int base = blockIdx.x * SCAN_CHUNK;
    int v[4], sum = 0;
    #pragma unroll
    for (int i = 0; i < 4; ++i) {
        int idx = base + t * 4 + i;
        v[i] = (idx < n) ? a[idx] : 0;
        sum += v[i];
    }
    s[t] = sum;
    __syncthreads();
    for (int off = 1; off < 256; off <<= 1) {
        int x = (t >= off) ? s[t - off] : 0;
        __syncthreads();
        s[t] += x;
        __syncthreads();
    }
    if (t == 255) bsum[blockIdx.x] = s[255];
    int run = s[t] - sum;
    #pragma unroll
    for (int i = 0; i < 4; ++i) {
        int idx = base + t * 4 + i;
        if (idx < n) a[idx] = run;
        run += v[i];
    }
}

__global__ void scan_phase2(int* __restrict__ bsum, int nb)
{
    if (threadIdx.x == 0 && blockIdx.x == 0) {
        int run = 0;
        for (int b = 0; b < nb; ++b) { int x = bsum[b]; bsum[b] = run; run += x; }
    }
}

__global__ __launch_bounds__(256) void scan_phase3(
    int* __restrict__ a, const int* __restrict__ bsum,
    int* __restrict__ cur, int n)
{
    int idx = blockIdx.x * 256 + threadIdx.x;
    if (idx < n) {
        int v = a[idx] + bsum[idx / SCAN_CHUNK];
        a[idx] = v;
        cur[idx] = v;
    }
}

__global__ __launch_bounds__(256) void edge_fill(
    const int* __restrict__ src, const int* __restrict__ dst,
    int* __restrict__ curs, int* __restrict__ curd,
    int* __restrict__ perms, int* __restrict__ permd)
{
    int e = blockIdx.x * 256 + threadIdx.x;
    if (e < N_EDGES) {
        int p1 = atomicAdd(&curs[src[e]], 1); perms[p1] = e;
        int p2 = atomicAdd(&curd[dst[e]], 1); permd[p2] = e;
    }
}

// ssrc[j]=src[perm_s[j]], sdst[j]=dst[perm_s[j]], ipos[perm_s[j]]=j
__global__ __launch_bounds__(256) void build_sorted(
    const int* __restrict__ src, const int* __restrict__ dst,
    const int* __restrict__ perms,
    int* __restrict__ ssrc, int* __restrict__ sdst, int* __restrict__ ipos)
{
    int j = blockIdx.x * 256 + threadIdx.x;
    if (j < N_EDGES) {
        int e = perms[j];
        ssrc[j] = src[e];
        sdst[j] = dst[e];
        ipos[e] = j;
    }
}

// pd2[i] = sorted-position of permd[i]  (dst-list -> xe row index)
__global__ __launch_bounds__(256) void build_pd2(
    const int* __restrict__ permd, const int* __restrict__ ipos,
    int* __restrict__ pd2)
{
    int i = blockIdx.x * 256 + threadIdx.x;
    if (i < N_EDGES) pd2[i] = ipos[permd[i]];
}

// ---------------------------------------------------------------------------
// Fused edge pipeline, 32 edges/block, split-bf16 MFMA layer 2 (validated r8)
// + T14 prefetch for B staging + red-buffer unioned into Bh (LDS 46.6->37.3KB
// -> 4 blocks/CU).
// ---------------------------------------------------------------------------
__global__ __launch_bounds__(256) void edge_fused_mfma(
    const float* __restrict__ uv,
    const int* __restrict__ eS, const int* __restrict__ eD,
    const float* __restrict__ be1,
    const unsigned short* __restrict__ We2Th, const unsigned short* __restrict__ We2Tl,
    const float* __restrict__ be2,
    const float* __restrict__ Wd, const float* __restrict__ bd,
    float* __restrict__ xe, float* __restrict__ preds, int last)
{
    __shared__ __align__(16) unsigned short H1h[32][136], H1l[32][136];
    __shared__ __align__(16) unsigned short Bh[128][40], Bl[128][40];
    __shared__ int sidx[32], didx[32];
    // decoder reduction buffer aliases Bh (dead after last K-slab's barrier):
    // 32*65*4 = 8320 B <= sizeof(Bh) = 10240 B
    float (*red)[65] = reinterpret_cast<float(*)[65]>(&Bh[0][0]);

    const int tid   = threadIdx.x;
    const int ebase = blockIdx.x * 32;
    const int w     = tid >> 6, lane = tid & 63;
    const int lr    = lane & 15, lg = lane >> 4;

    us8 pbh[2], pbl[2];
    auto loadB = [&](int kb) {
        #pragma unroll
        for (int i = 0; i < 2; ++i) {
            int u = tid + i * 256;
            int col = u >> 2, c8 = (u & 3) << 3;
            size_t goff = (size_t)col * 128 + kb + c8;
            pbh[i] = *(const us8*)(We2Th + goff);
            pbl[i] = *(const us8*)(We2Tl + goff);
        }
    };
    auto writeB = [&]() {
        #pragma unroll
        for (int i = 0; i < 2; ++i) {
            int u = tid + i * 256;
            int col = u >> 2, c8 = (u & 3) << 3;
            *(us8*)&Bh[col][c8] = pbh[i];
            *(us8*)&Bl[col][c8] = pbl[i];
        }
    };

    loadB(0);                       // in flight across index staging + gather

    if (tid < 32)       sidx[tid]      = eS[ebase + tid];
    else if (tid < 64)  didx[tid - 32] = eD[ebase + tid - 32];
    __syncthreads();

    // ---- layer 1: gather u[src]+v[dst]+bias, relu, split-store to LDS ----
    const float2 bias1 = *(const float2*)(be1 + lane * 2);
    #pragma unroll
    for (int i = 0; i < 8; ++i) {
        int e = w * 8 + i;
        int s = sidx[e], d = didx[e];
        float2 a = *(const float2*)(uv + (size_t)s * 256 + lane * 2);
        float2 b = *(const float2*)(uv + (size_t)d * 256 + 128 + lane * 2);
        float hx = fmaxf(a.x + b.x + bias1.x, 0.f);
        float hy = fmaxf(a.y + b.y + bias1.y, 0.f);
        ushort2 vh, vl;
        vh.x = f2bf(hx); vl.x = f2bf(hx - bf2f(vh.x));
        vh.y = f2bf(hy); vl.y = f2bf(hy - bf2f(vh.y));
        *(ushort2*)&H1h[e][lane * 2] = vh;
        *(ushort2*)&H1l[e][lane * 2] = vl;
    }
    writeB();
    __syncthreads();                // H1 + B slab 0 visible

    f32x4 acc[2][2];
    #pragma unroll
    for (int i = 0; i < 2; ++i)
        #pragma unroll
        for (int j = 0; j < 2; ++j)
            acc[i][j] = (f32x4)(0.0f);

    for (int kb = 0; kb < 128; kb += 32) {
        const bool more = kb < 96;
        if (more) loadB(kb + 32);   // in flight during ds reads + MFMA

        bf16x8 fah[2], fal[2], fbh[2], fbl[2];
        #pragma unroll
        for (int mt = 0; mt < 2; ++mt) {
            int r = mt * 16 + lr;
            fah[mt] = *(const bf16x8*)&H1h[r][kb + lg * 8];
            fal[mt] = *(const bf16x8*)&H1l[r][kb + lg * 8];
        }
        #pragma unroll
        for (int nt = 0; nt < 2; ++nt) {
            int c = w * 32 + nt * 16 + lr;
            fbh[nt] = *(const bf16x8*)&Bh[c][lg * 8];
            fbl[nt] = *(const bf16x8*)&Bl[c][lg * 8];
        }
        #pragma unroll
        for (int mt = 0; mt < 2; ++mt)
            #pragma unroll
            for (int nt = 0; nt < 2; ++nt) {
                acc[mt][nt] = __builtin_amdgcn_mfma_f32_16x16x32_bf16(
                    fah[mt], fbh[nt], acc[mt][nt], 0, 0, 0);
                acc[mt][nt] = __builtin_amdgcn_mfma_f32_16x16x32_bf16(
                    fah[mt], fbl[nt], acc[mt][nt], 0, 0, 0);
                acc[mt][nt] = __builtin_amdgcn_mfma_f32_16x16x32_bf16(
                    fal[mt], fbh[nt], acc[mt][nt], 0, 0, 0);
            }
        __syncthreads();
        if (more) {
            writeB();
            __syncthreads();
        }
    }

    // ---- epilogue: bias+relu, store xe, optional fused decoder ----
    float partial[2][4] = {};
    #pragma unroll
    for (int nt = 0; nt < 2; ++nt) {
        int cg = w * 32 + nt * 16 + lr;
        float bias2 = be2[cg];
        float wdv = last ? Wd[cg] : 0.f;
        #pragma unroll
        for (int mt = 0; mt < 2; ++mt)
            #pragma unroll
            for (int q = 0; q < 4; ++q) {
                int r = mt * 16 + lg * 4 + q;
                float v = fmaxf(acc[mt][nt][q] + bias2, 0.f);
                xe[(size_t)(ebase + r) * 128 + cg] = v;
                partial[mt][q] += v * wdv;
            }
    }
    if (last) {
        // red aliases Bh: all MFMA reads of Bh completed at the loop's final
        // __syncthreads(); safe to overwrite now.
        #pragma unroll
        for (int mt = 0; mt < 2; ++mt)
            #pragma unroll
            for (int q = 0; q < 4; ++q)
                red[mt * 16 + lg * 4 + q][w * 16 + lr] = partial[mt][q];
        __syncthreads();
        if (tid < 32) {
            float s = 0.f;
            #pragma unroll
            for (int j = 0; j < 64; ++j) s += red[tid][j];
            preds[ebase + tid] = 1.f / (1.f + expf(-(s + bd[0])));
        }
    }
}

// ---------------------------------------------------------------------------
// Atomic-free scatter (validated r8): src-half streams contiguous xe rows,
// dst-half gathers rows pd2[i]; 4-deep ILP.
// ---------------------------------------------------------------------------
__global__ __launch_bounds__(256) void node_accum(
    const float* __restrict__ xe,
    const int* __restrict__ rps,
    const int* __restrict__ rpd, const int* __restrict__ pd2,
    float* __restrict__ x2h)
{
    const int wave = threadIdx.x >> 6, lane = threadIdx.x & 63;
    const int nid = blockIdx.x * 4 + wave;
    if (nid >= N_NODES) return;
    const int c = lane * 2;

    const int s0 = rps[nid];
    const int s1 = (nid == N_NODES - 1) ? N_EDGES : rps[nid + 1];
    const int d0 = rpd[nid];
    const int d1 = (nid == N_NODES - 1) ? N_EDGES : rpd[nid + 1];

    float2 a = make_float2(0.f, 0.f), b = make_float2(0.f, 0.f);
    int is = s0, id = d0;

    while (is + 2 <= s1 && id + 2 <= d1) {
        float2 v0 = *(const float2*)(xe + (size_t)is * 128 + c);
        float2 v1 = *(const float2*)(xe + (size_t)(is + 1) * 128 + c);
        int f0 = pd2[id], f1 = pd2[id + 1];
        float2 w0 = *(const float2*)(xe + (size_t)f0 * 128 + c);
        float2 w1 = *(const float2*)(xe + (size_t)f1 * 128 + c);
        a.x += v0.x + v1.x; a.y += v0.y + v1.y;
        b.x += w0.x + w1.x; b.y += w0.y + w1.y;
        is += 2; id += 2;
    }
    while (is < s1) {
        float2 v = *(const float2*)(xe + (size_t)is * 128 + c);
        a.x += v.x; a.y += v.y; ++is;
    }
    while (id < d1) {
        int f = pd2[id];
        float2 w = *(const float2*)(xe + (size_t)f * 128 + c);
        b.x += w.x; b.y += w.y; ++id;
    }

    *(float2*)(x2h + (size_t)nid * 256 + c) = a;
    *(float2*)(x2h + (size_t)nid * 256 + 128 + c) = b;
}

// ---------------------------------------------------------------------------
extern "C" void kernel_launch(void* const* d_in, const int* in_sizes, int n_in,
                              void* d_out, int out_size, void* d_ws, size_t ws_size,
                              hipStream_t stream)
{
    const float* inputs = (const float*)d_in[0];
    const float* W_n11  = (const float*)d_in[1];
    const float* b_n11  = (const float*)d_in[2];
    const float* W_n21  = (const float*)d_in[3];
    const float* b_n21  = (const float*)d_in[4];
    const float* W_n22  = (const float*)d_in[5];
    const float* b_n22  = (const float*)d_in[6];
    const float* W_e11  = (const float*)d_in[7];
    const float* b_e11  = (const float*)d_in[8];
    const float* W_e12  = (const float*)d_in[9];
    const float* b_e12  = (const float*)d_in[10];
    const float* W_dec  = (const float*)d_in[11];
    const float* b_dec  = (const float*)d_in[12];
    const int*   src    = (const int*)d_in[13];
    const int*   dst    = (const int*)d_in[14];

    // ws layout (~114 MB): buf [N,256] fp32 | CSR ints | sorted idx | weights
    float* buf  = (float*)d_ws;
    int* rp_s   = (int*)(buf + (size_t)N_NODES * 256);
    int* rp_d   = rp_s + N_NODES;
    int* cur_s  = rp_d + N_NODES;
    int* cur_d  = cur_s + N_NODES;
    int* perm_s = cur_d + N_NODES;
    int* perm_d = perm_s + N_EDGES;
    int* bsum_s = perm_d + N_EDGES;
    int* bsum_d = bsum_s + 128;
    int* ssrc   = bsum_d + 128;
    int* sdst   = ssrc + N_EDGES;
    int* ipos   = sdst + N_EDGES;
    int* pd2    = ipos + N_EDGES;
    unsigned short* n11Th  = (unsigned short*)(pd2 + N_EDGES);
    unsigned short* n11Tl  = n11Th + 64 * 256;
    unsigned short* n21Th  = n11Tl + 64 * 256;
    unsigned short* n21Tl  = n21Th + 256 * 128;
    unsigned short* n22Th  = n21Tl + 256 * 128;
    unsigned short* n22Tl  = n22Th + 128 * 128;
    unsigned short* wcatTh = n22Tl + 128 * 128;
    unsigned short* wcatTl = wcatTh + 256 * 128;
    unsigned short* e12Th  = wcatTl + 256 * 128;
    unsigned short* e12Tl  = e12Th + 128 * 128;

    float* x2h = buf;   // aliases by phase (lifetimes disjoint per iter)
    float* uv  = buf;

    float* preds = (float*)d_out;
    float* z     = preds + N_EDGES;         // [E,128] region of d_out

    float* tmp = z;
    float* xh  = z + (size_t)N_NODES * 128;
    float* xe  = z;

    const int mBlks    = (N_NODES + 127) / 128;
    const int scanBlks = (N_NODES + SCAN_CHUNK - 1) / SCAN_CHUNK;
    const int nodeBlks = (N_NODES + 255) / 256;
    const int edgeBlks = (N_EDGES + 255) / 256;

    // ---- per-launch setup ----
    repack_T_split<<<(64 * 256 + 255) / 256, 256, 0, stream>>>(W_n11, n11Th, n11Tl, 64, 256);
    repack_T_split<<<(256 * 128 + 255) / 256, 256, 0, stream>>>(W_n21, n21Th, n21Tl, 256, 128);
    repack_T_split<<<(128 * 128 + 255) / 256, 256, 0, stream>>>(W_n22, n22Th, n22Tl, 128, 128);
    repack_T_split<<<(128 * 128 + 255) / 256, 256, 0, stream>>>(W_e12, e12Th, e12Tl, 128, 128);
    repack_we11_T_split<<<(128 * 256 + 255) / 256, 256, 0, stream>>>(W_e11, wcatTh, wcatTl);

    hipMemsetAsync(rp_s, 0, 2 * N_NODES * sizeof(int), stream);
    edge_hist<<<edgeBlks, 256, 0, stream>>>(src, dst, rp_s, rp_d);
    scan_phase1<<<scanBlks, 256, 0, stream>>>(rp_s, bsum_s, N_NODES);
    scan_phase1<<<scanBlks, 256, 0, stream>>>(rp_d, bsum_d, N_NODES);
    scan_phase2<<<1, 64, 0, stream>>>(bsum_s, scanBlks);
    scan_phase2<<<1, 64, 0, stream>>>(bsum_d, scanBlks);
    scan_phase3<<<nodeBlks, 256, 0, stream>>>(rp_s, bsum_s, cur_s, N_NODES);
    scan_phase3<<<nodeBlks, 256, 0, stream>>>(rp_d, bsum_d, cur_d, N_NODES);
    edge_fill<<<edgeBlks, 256, 0, stream>>>(src, dst, cur_s, cur_d, perm_s, perm_d);
    build_sorted<<<edgeBlks, 256, 0, stream>>>(src, dst, perm_s, ssrc, sdst, ipos);
    build_pd2<<<edgeBlks, 256, 0, stream>>>(perm_d, ipos, pd2);

    // ---- node encoder: [N,64] -> [N,256] ----
    gemm_mfma<<<dim3(mBlks, 2), 256, 0, stream>>>(
        inputs, n11Th, n11Tl, b_n11, x2h, N_NODES, 64, 256, 1);

    for (int it = 0; it < 3; ++it) {
        const int last = (it == 2);
        gemm_mfma<<<dim3(mBlks, 1), 256, 0, stream>>>(
            x2h, n21Th, n21Tl, b_n21, tmp, N_NODES, 256, 128, 1);
        gemm_mfma<<<dim3(mBlks, 1), 256, 0, stream>>>(
            tmp, n22Th, n22Tl, b_n22, xh, N_NODES, 128, 128, 1);
        gemm_mfma<<<dim3(mBlks, 2), 256, 0, stream>>>(
            xh, wcatTh, wcatTl, nullptr, uv, N_NODES, 128, 256, 0);
        // scatter iters process edges in src-sorted order (xe row j = edge
        // perm_s[j]); last iter uses natural order so xe == z layout.
        edge_fused_mfma<<<N_EDGES / 32, 256, 0, stream>>>(
            uv, last ? src : ssrc, last ? dst : sdst, b_e11,
            e12Th, e12Tl, b_e12, W_dec, b_dec, xe, preds, last);
        if (!last)
            node_accum<<<(N_NODES + 3) / 4, 256, 0, stream>>>(
                xe, rp_s, rp_d, pd2, x2h);
    }
}